// Round 5
// baseline (725.107 us; speedup 1.0000x reference)
//
#include <hip/hip_runtime.h>
#include <math.h>

static constexpr int NN = 8192;      // nodes
static constexpr int NE = 262144;    // edges
static constexpr int NCH = 8;        // K-chunks for flash partials
static constexpr int NS = (NN / NCH) / 32;  // 32 steps per chunk

typedef short bfrag __attribute__((ext_vector_type(8)));   // 8 bf16 (A/B frag)
typedef float f32x4 __attribute__((ext_vector_type(4)));   // C/D frag

#define MFMA(a, b, c) __builtin_amdgcn_mfma_f32_16x16x32_bf16((a), (b), (c), 0, 0, 0)

__device__ __forceinline__ unsigned short f2bf(float x) {
  union { float f; unsigned u; } v; v.f = x;
  unsigned r = v.u + 0x7fffu + ((v.u >> 16) & 1u);  // RNE
  return (unsigned short)(r >> 16);
}
__device__ __forceinline__ float bf2f(unsigned short h) {
  union { unsigned u; float f; } v; v.u = ((unsigned)h) << 16;
  return v.f;
}

__device__ __forceinline__ void gll16(const void* g, void* l) {
  __builtin_amdgcn_global_load_lds(
      (const __attribute__((address_space(1))) unsigned*)g,
      (__attribute__((address_space(3))) unsigned*)l, 16, 0, 0);
}

// ---------------- graph prep ----------------

__global__ void k_count2(const int* __restrict__ d1, const int* __restrict__ d2,
                         int* __restrict__ i1, int* __restrict__ i2) {
  int t = blockIdx.x * 256 + threadIdx.x;
  const int* d = blockIdx.y ? d2 : d1;
  int* ii = blockIdx.y ? i2 : i1;
  if (t < NE) atomicAdd(&ii[d[t]], 1);
}

// shfl-based block scan: 3 barriers per 1024-chunk instead of ~20
__global__ void k_scan2(const int* __restrict__ ideg1, int* __restrict__ off1,
                        int* __restrict__ cur1, float* __restrict__ dinv1,
                        const int* __restrict__ ideg2, int* __restrict__ off2,
                        int* __restrict__ cur2, float* __restrict__ dinv2) {
  const int* indeg = blockIdx.x ? ideg2 : ideg1;
  int* off = blockIdx.x ? off2 : off1;
  int* cur = blockIdx.x ? cur2 : cur1;
  float* dinv = blockIdx.x ? dinv2 : dinv1;
  __shared__ int wsum[16];
  int t = threadIdx.x, lane = t & 63, wv = t >> 6;
  int carry = 0;
  for (int base = 0; base < NN; base += 1024) {
    int v = indeg[base + t];
    int sc = v;
#pragma unroll
    for (int d = 1; d < 64; d <<= 1) {
      int o = __shfl_up(sc, d);
      if (lane >= d) sc += o;
    }
    if (lane == 63) wsum[wv] = sc;
    __syncthreads();
    if (t < 16) {
      int w = wsum[t];
#pragma unroll
      for (int d = 1; d < 16; d <<= 1) {
        int o = __shfl_up(w, d);
        if (t >= d) w += o;
      }
      wsum[t] = w;
    }
    __syncthreads();
    int excl = carry + (wv ? wsum[wv - 1] : 0) + sc - v;
    off[base + t] = excl;
    cur[base + t] = excl;
    dinv[base + t] = 1.0f / sqrtf((float)(v + 1));  // +1 self loop
    carry += wsum[15];
    __syncthreads();
  }
  if (t == 0) off[NN] = carry;
}

__global__ void k_fill2(const int* __restrict__ s1, const int* __restrict__ d1,
                        int* __restrict__ c1, int* __restrict__ l1,
                        const int* __restrict__ s2, const int* __restrict__ d2,
                        int* __restrict__ c2, int* __restrict__ l2) {
  int t = blockIdx.x * 256 + threadIdx.x;
  const int* src = blockIdx.y ? s2 : s1;
  const int* dst = blockIdx.y ? d2 : d1;
  int* cur = blockIdx.y ? c2 : c1;
  int* out = blockIdx.y ? l2 : l1;
  if (t < NE) {
    int d = dst[t];
    int slot = atomicAdd(&cur[d], 1);
    out[slot] = src[t];
  }
}

// ---------------- weight transpose + split (all 10 matrices, one launch) ----------------

__global__ void k_split_w(const float* W11, const float* W21, const float* W12,
                          const float* W22, const float* q1, const float* k1,
                          const float* v1, const float* q2, const float* k2,
                          const float* v2, short* __restrict__ whi,
                          short* __restrict__ wlo) {
  int y = blockIdx.y;
  const float* src; int R, C, base;
  if (y == 0)      { src = W11; R = 128; C = 256; base = 0; }
  else if (y == 1) { src = W21; R = 128; C = 256; base = 32768; }
  else if (y == 2) { src = W12; R = 256; C = 64;  base = 65536; }
  else if (y == 3) { src = W22; R = 256; C = 64;  base = 81920; }
  else if (y == 4) { src = q1;  R = 64;  C = 64;  base = 98304; }
  else if (y == 5) { src = k1;  R = 64;  C = 64;  base = 102400; }
  else if (y == 6) { src = v1;  R = 64;  C = 64;  base = 106496; }
  else if (y == 7) { src = q2;  R = 64;  C = 64;  base = 110592; }
  else if (y == 8) { src = k2;  R = 64;  C = 64;  base = 114688; }
  else             { src = v2;  R = 64;  C = 64;  base = 118784; }
  int idx = blockIdx.x * 256 + threadIdx.x;
  if (idx >= R * C) return;
  int r = idx / C, c = idx % C;
  float x = src[idx];
  unsigned short h = f2bf(x);
  whi[base + c * R + r] = (short)h;
  wlo[base + c * R + r] = (short)f2bf(x - bf2f(h));
}

// ---------------- layer-1 aggregation on raw x (D=128), wave per node, both branches ----------------

__global__ __launch_bounds__(256) void k_agg1d(
    const float* __restrict__ x1, const float* __restrict__ x2,
    const int* __restrict__ off1, const int* __restrict__ srcl1,
    const float* __restrict__ dinv1, const int* __restrict__ off2,
    const int* __restrict__ srcl2, const float* __restrict__ dinv2,
    short* __restrict__ a1hi, short* __restrict__ a1lo,
    short* __restrict__ a2hi, short* __restrict__ a2lo) {
  int br = blockIdx.y;
  const float* x = br ? x2 : x1;
  const int* off = br ? off2 : off1;
  const int* srcl = br ? srcl2 : srcl1;
  const float* dinv = br ? dinv2 : dinv1;
  short* ahi = br ? a2hi : a1hi;
  short* alo = br ? a2lo : a1lo;
  int wave = threadIdx.x >> 6, lane = threadIdx.x & 63;
  int node = blockIdx.x * 4 + wave;
  float dn = dinv[node];
  const float2* xr = (const float2*)x;
  float ax, ay;
  { float2 v = xr[(size_t)node * 64 + lane]; ax = dn * v.x; ay = dn * v.y; }
  int p = off[node], e = off[node + 1];
  for (; p + 3 < e; p += 4) {
    int s0 = srcl[p], s1 = srcl[p + 1], s2 = srcl[p + 2], s3 = srcl[p + 3];
    float w0 = dinv[s0], w1 = dinv[s1], w2 = dinv[s2], w3 = dinv[s3];
    float2 v0 = xr[(size_t)s0 * 64 + lane], v1 = xr[(size_t)s1 * 64 + lane];
    float2 v2 = xr[(size_t)s2 * 64 + lane], v3 = xr[(size_t)s3 * 64 + lane];
    ax += w0 * v0.x + w1 * v1.x + w2 * v2.x + w3 * v3.x;
    ay += w0 * v0.y + w1 * v1.y + w2 * v2.y + w3 * v3.y;
  }
  for (; p < e; ++p) {
    int s = srcl[p];
    float w = dinv[s];
    float2 v = xr[(size_t)s * 64 + lane];
    ax += w * v.x; ay += w * v.y;
  }
  float ox = dn * ax, oy = dn * ay;
  unsigned short hx = f2bf(ox), hy = f2bf(oy);
  int o = node * 128 + lane * 2;
  *(short2*)(ahi + o) = make_short2((short)hx, (short)hy);
  *(short2*)(alo + o) = make_short2((short)f2bf(ox - bf2f(hx)),
                                    (short)f2bf(oy - bf2f(hy)));
}

// ---------------- layer-2 aggregation (D=64) + bias, wave per node, both branches ----------------

__global__ __launch_bounds__(256) void k_agg2d(
    const float* __restrict__ t1, const float* __restrict__ t2,
    const int* __restrict__ off1, const int* __restrict__ srcl1,
    const float* __restrict__ dinv1, const int* __restrict__ off2,
    const int* __restrict__ srcl2, const float* __restrict__ dinv2,
    const float* __restrict__ b12, const float* __restrict__ b22,
    short* __restrict__ g1hi, short* __restrict__ g1lo,
    short* __restrict__ g2hi, short* __restrict__ g2lo) {
  int br = blockIdx.y;
  const float* t = br ? t2 : t1;
  const int* off = br ? off2 : off1;
  const int* srcl = br ? srcl2 : srcl1;
  const float* dinv = br ? dinv2 : dinv1;
  const float* bias = br ? b22 : b12;
  short* ghi = br ? g2hi : g1hi;
  short* glo = br ? g2lo : g1lo;
  int wave = threadIdx.x >> 6, lane = threadIdx.x & 63;
  int node = blockIdx.x * 4 + wave;
  float dn = dinv[node];
  float acc = dn * t[(size_t)node * 64 + lane];
  int p = off[node], e = off[node + 1];
  for (; p + 3 < e; p += 4) {
    int s0 = srcl[p], s1 = srcl[p + 1], s2 = srcl[p + 2], s3 = srcl[p + 3];
    float w0 = dinv[s0], w1 = dinv[s1], w2 = dinv[s2], w3 = dinv[s3];
    acc += w0 * t[(size_t)s0 * 64 + lane] + w1 * t[(size_t)s1 * 64 + lane] +
           w2 * t[(size_t)s2 * 64 + lane] + w3 * t[(size_t)s3 * 64 + lane];
  }
  for (; p < e; ++p) {
    int s = srcl[p];
    acc += dinv[s] * t[(size_t)s * 64 + lane];
  }
  float o = dn * acc + bias[lane];
  unsigned short h = f2bf(o);
  ghi[(size_t)node * 64 + lane] = (short)h;
  glo[(size_t)node * 64 + lane] = (short)f2bf(o - bf2f(h));
}

// ---------------- GCN layer-1 GEMM (K=128, N=256, bias+relu, hl out), both branches ----------------

__global__ __launch_bounds__(64) void k_gemmL1(
    const short* __restrict__ a1hi, const short* __restrict__ a1lo,
    const short* __restrict__ a2hi, const short* __restrict__ a2lo,
    const short* __restrict__ whi, const short* __restrict__ wlo,
    const float* __restrict__ b11, const float* __restrict__ b21,
    short* __restrict__ h1hi, short* __restrict__ h1lo,
    short* __restrict__ h2hi, short* __restrict__ h2lo) {
  int br = blockIdx.z;
  const short* Ahi = br ? a2hi : a1hi;
  const short* Alo = br ? a2lo : a1lo;
  const short* Bh = whi + (br ? 32768 : 0);
  const short* Bl = wlo + (br ? 32768 : 0);
  const float* bias = br ? b21 : b11;
  short* Chi = br ? h2hi : h1hi;
  short* Clo = br ? h2lo : h1lo;
  int lane = threadIdx.x;
  int lo16 = lane & 15, hi4 = lane >> 4;
  int r0 = blockIdx.x * 16;
  int c0 = blockIdx.y * 64;
  bfrag ah[4], al[4];
  const char* abh = (const char*)Ahi + ((size_t)(r0 + lo16) * 128 + hi4 * 8) * 2;
  const char* abl = (const char*)Alo + ((size_t)(r0 + lo16) * 128 + hi4 * 8) * 2;
#pragma unroll
  for (int ks = 0; ks < 4; ++ks) {
    ah[ks] = *(const bfrag*)(abh + ks * 64);
    al[ks] = *(const bfrag*)(abl + ks * 64);
  }
  f32x4 z = {0.f, 0.f, 0.f, 0.f};
  f32x4 acc[4] = {z, z, z, z};
#pragma unroll
  for (int c = 0; c < 4; ++c) {
    const char* bbh = (const char*)Bh + ((size_t)(c0 + c * 16 + lo16) * 128 + hi4 * 8) * 2;
    const char* bbl = (const char*)Bl + ((size_t)(c0 + c * 16 + lo16) * 128 + hi4 * 8) * 2;
#pragma unroll
    for (int ks = 0; ks < 4; ++ks) {
      bfrag bh = *(const bfrag*)(bbh + ks * 64);
      bfrag bl = *(const bfrag*)(bbl + ks * 64);
      acc[c] = MFMA(ah[ks], bh, acc[c]);
      acc[c] = MFMA(ah[ks], bl, acc[c]);
      acc[c] = MFMA(al[ks], bh, acc[c]);
    }
  }
#pragma unroll
  for (int c = 0; c < 4; ++c) {
    int col = c0 + c * 16 + lo16;
    float bv = bias[col];
#pragma unroll
    for (int r = 0; r < 4; ++r) {
      int row = r0 + hi4 * 4 + r;
      float v = fmaxf(acc[c][r] + bv, 0.f);
      unsigned short h = f2bf(v);
      Chi[(size_t)row * 256 + col] = (short)h;
      Clo[(size_t)row * 256 + col] = (short)f2bf(v - bf2f(h));
    }
  }
}

// ---------------- GCN layer-2 GEMM (K=256, N=64, f32 out), both branches ----------------

__global__ __launch_bounds__(64) void k_gemmL2(
    const short* __restrict__ h1hi, const short* __restrict__ h1lo,
    const short* __restrict__ h2hi, const short* __restrict__ h2lo,
    const short* __restrict__ whi, const short* __restrict__ wlo,
    float* __restrict__ t1, float* __restrict__ t2) {
  int br = blockIdx.y;
  const short* Ahi = br ? h2hi : h1hi;
  const short* Alo = br ? h2lo : h1lo;
  const short* Bh = whi + (br ? 81920 : 65536);
  const short* Bl = wlo + (br ? 81920 : 65536);
  float* Cf = br ? t2 : t1;
  int lane = threadIdx.x;
  int lo16 = lane & 15, hi4 = lane >> 4;
  int r0 = blockIdx.x * 16;
  bfrag ah[8], al[8];
  const char* abh = (const char*)Ahi + ((size_t)(r0 + lo16) * 256 + hi4 * 8) * 2;
  const char* abl = (const char*)Alo + ((size_t)(r0 + lo16) * 256 + hi4 * 8) * 2;
#pragma unroll
  for (int ks = 0; ks < 8; ++ks) {
    ah[ks] = *(const bfrag*)(abh + ks * 64);
    al[ks] = *(const bfrag*)(abl + ks * 64);
  }
  f32x4 z = {0.f, 0.f, 0.f, 0.f};
  f32x4 acc[4] = {z, z, z, z};
#pragma unroll
  for (int c = 0; c < 4; ++c) {
    const char* bbh = (const char*)Bh + ((size_t)(c * 16 + lo16) * 256 + hi4 * 8) * 2;
    const char* bbl = (const char*)Bl + ((size_t)(c * 16 + lo16) * 256 + hi4 * 8) * 2;
#pragma unroll
    for (int ks = 0; ks < 8; ++ks) {
      bfrag bh = *(const bfrag*)(bbh + ks * 64);
      bfrag bl = *(const bfrag*)(bbl + ks * 64);
      acc[c] = MFMA(ah[ks], bh, acc[c]);
      acc[c] = MFMA(ah[ks], bl, acc[c]);
      acc[c] = MFMA(al[ks], bh, acc[c]);
    }
  }
#pragma unroll
  for (int c = 0; c < 4; ++c) {
    int col = c * 16 + lo16;
#pragma unroll
    for (int r = 0; r < 4; ++r)
      Cf[(size_t)(r0 + hi4 * 4 + r) * 64 + col] = acc[c][r];
  }
}

// ---------------- QKV projections; V writes transposed hi/lo directly ----------------

__global__ __launch_bounds__(64) void k_qkv(
    const short* __restrict__ Aqhi, const short* __restrict__ Aqlo,
    const short* __restrict__ Akhi, const short* __restrict__ Aklo,
    const short* __restrict__ Avhi, const short* __restrict__ Avlo,
    const short* __restrict__ whi, const short* __restrict__ wlo,
    int bq, int bk, int bv,
    short* __restrict__ Qhi, short* __restrict__ Qlo,
    short* __restrict__ Khi, short* __restrict__ Klo,
    short* __restrict__ Vthi, short* __restrict__ Vtlo) {
  int y = blockIdx.y;
  const short *Ah, *Al;
  int boff;
  if (y == 0)      { Ah = Aqhi; Al = Aqlo; boff = bq; }
  else if (y == 1) { Ah = Akhi; Al = Aklo; boff = bk; }
  else             { Ah = Avhi; Al = Avlo; boff = bv; }
  const short* Bh = whi + boff;
  const short* Bl = wlo + boff;
  int lane = threadIdx.x;
  int lo16 = lane & 15, hi4 = lane >> 4;
  int r0 = blockIdx.x * 16;
  bfrag ah0, ah1, al0, al1;
  {
    const char* a = (const char*)(Ah + (size_t)(r0 + lo16) * 64 + hi4 * 8);
    const char* b = (const char*)(Al + (size_t)(r0 + lo16) * 64 + hi4 * 8);
    ah0 = *(const bfrag*)a; ah1 = *(const bfrag*)(a + 64);
    al0 = *(const bfrag*)b; al1 = *(const bfrag*)(b + 64);
  }
  f32x4 z = {0.f, 0.f, 0.f, 0.f};
  f32x4 acc[4] = {z, z, z, z};
#pragma unroll
  for (int c = 0; c < 4; ++c) {
    const char* bbh = (const char*)(Bh + (size_t)(c * 16 + lo16) * 64 + hi4 * 8);
    const char* bbl = (const char*)(Bl + (size_t)(c * 16 + lo16) * 64 + hi4 * 8);
    bfrag bh0 = *(const bfrag*)bbh, bh1 = *(const bfrag*)(bbh + 64);
    bfrag bl0 = *(const bfrag*)bbl, bl1 = *(const bfrag*)(bbl + 64);
    acc[c] = MFMA(ah0, bh0, acc[c]);
    acc[c] = MFMA(ah1, bh1, acc[c]);
    acc[c] = MFMA(ah0, bl0, acc[c]);
    acc[c] = MFMA(ah1, bl1, acc[c]);
    acc[c] = MFMA(al0, bh0, acc[c]);
    acc[c] = MFMA(al1, bh1, acc[c]);
  }
  if (y == 2) {
    // V: write transposed split directly. Lane owns rows r0+hi4*4..+3 of col.
#pragma unroll
    for (int c = 0; c < 4; ++c) {
      int col = c * 16 + lo16;
      short4 vh, vl;
      float v0 = acc[c][0], v1 = acc[c][1], v2 = acc[c][2], v3 = acc[c][3];
      unsigned short h0 = f2bf(v0), h1 = f2bf(v1), h2 = f2bf(v2), h3 = f2bf(v3);
      vh = make_short4((short)h0, (short)h1, (short)h2, (short)h3);
      vl = make_short4((short)f2bf(v0 - bf2f(h0)), (short)f2bf(v1 - bf2f(h1)),
                       (short)f2bf(v2 - bf2f(h2)), (short)f2bf(v3 - bf2f(h3)));
      size_t o = (size_t)col * NN + r0 + hi4 * 4;
      *(short4*)(Vthi + o) = vh;
      *(short4*)(Vtlo + o) = vl;
    }
  } else {
    short* oh = (y == 0) ? Qhi : Khi;
    short* ol = (y == 0) ? Qlo : Klo;
#pragma unroll
    for (int c = 0; c < 4; ++c) {
      int col = c * 16 + lo16;
#pragma unroll
      for (int r = 0; r < 4; ++r) {
        int row = r0 + hi4 * 4 + r;
        float v = acc[c][r];
        unsigned short h = f2bf(v);
        oh[(size_t)row * 64 + col] = (short)h;
        ol[(size_t)row * 64 + col] = (short)f2bf(v - bf2f(h));
      }
    }
  }
}

// ---------------- MFMA flash attention v5 ----------------
// 4 waves x 32 Q rows (2 tiles/wave); grid (NN/128, NCH); counted-vmcnt pipeline.
// K tile 32x64 hl + Vt tile 64x32 hl double-buffered; each wave stages 4 gll16/step.

__global__ __launch_bounds__(256) void k_attn_v5(
    const short* __restrict__ Qhi, const short* __restrict__ Qlo,
    const short* __restrict__ Khi_g, const short* __restrict__ Klo_g,
    const short* __restrict__ Vthi_g, const short* __restrict__ Vtlo_g,
    float* __restrict__ Opart, float* __restrict__ mpart, float* __restrict__ lpart) {
  __shared__ short skh[2][32 * 64], skl[2][32 * 64];
  __shared__ short svh[2][64 * 32], svl[2][64 * 32];
  __shared__ short plds[8][16 * 40];
  const int tid = threadIdx.x;
  const int wave = tid >> 6, lane = tid & 63;
  const int lo16 = lane & 15, hi4 = lane >> 4;
  const int q0 = blockIdx.x * 128 + wave * 32;
  const int j0 = blockIdx.y * (NN / NCH);
  short* mypA = plds[wave * 2];
  short* mypB = plds[wave * 2 + 1];

  // staging: each of 4 waves stages 8 K-rows (hi+lo) and 16 Vt-rows (hi+lo)
  const int krow = wave * 8 + (lane >> 3);
  const int kcbs = ((lane & 7) * 16) ^ ((krow & 7) << 4);
  const int vrow = wave * 16 + (lane >> 2);
  const int vcbs = ((lane & 3) * 16) ^ (((vrow >> 1) & 3) << 4);
  const char* gka = (const char*)Khi_g + (size_t)(j0 + krow) * 128 + kcbs;
  const char* gkb = (const char*)Klo_g + (size_t)(j0 + krow) * 128 + kcbs;
  const char* gva = (const char*)Vthi_g + (size_t)vrow * (NN * 2) + (size_t)j0 * 2 + vcbs;
  const char* gvb = (const char*)Vtlo_g + (size_t)vrow * (NN * 2) + (size_t)j0 * 2 + vcbs;

#define STAGE(buf, s)                                                \
  do {                                                               \
    gll16(gka + (size_t)(s) * 4096, (char*)skh[buf] + wave * 1024);  \
    gll16(gkb + (size_t)(s) * 4096, (char*)skl[buf] + wave * 1024);  \
    gll16(gva + (s) * 64, (char*)svh[buf] + wave * 1024);            \
    gll16(gvb + (s) * 64, (char*)svl[buf] + wave * 1024);            \
  } while (0)

  // Q fragments for both tiles (registers, whole sweep)
  const bfrag* qphA = (const bfrag*)(Qhi + (size_t)(q0 + lo16) * 64 + hi4 * 8);
  const bfrag* qplA = (const bfrag*)(Qlo + (size_t)(q0 + lo16) * 64 + hi4 * 8);
  const bfrag* qphB = (const bfrag*)(Qhi + (size_t)(q0 + 16 + lo16) * 64 + hi4 * 8);
  const bfrag* qplB = (const bfrag*)(Qlo + (size_t)(q0 + 16 + lo16) * 64 + hi4 * 8);
  bfrag qh0A = qphA[0], qh1A = qphA[4], ql0A = qplA[0], ql1A = qplA[4];
  bfrag qh0B = qphB[0], qh1B = qphB[4], ql0B = qplB[0], ql1B = qplB[4];

  f32x4 z = {0.f, 0.f, 0.f, 0.f};
  f32x4 oaccA[4] = {z, z, z, z}, oaccB[4] = {z, z, z, z};
  float mrunA[4] = {-1e30f, -1e30f, -1e30f, -1e30f};
  float mrunB[4] = {-1e30f, -1e30f, -1e30f, -1e30f};
  float lsumA[4] = {0.f, 0.f, 0.f, 0.f}, lsumB[4] = {0.f, 0.f, 0.f, 0.f};

#define SMAX(sa, mrun, lsum, oacc, myp, pa)                                   \
  do {                                                                        \
    _Pragma("unroll") for (int t = 0; t < 2; ++t)                             \
      _Pragma("unroll") for (int r = 0; r < 4; ++r) {                         \
        float v = sa[t][r];                                                   \
        sa[t][r] = fmaxf(v, 0.01f * v);                                       \
      }                                                                       \
    float pm[4];                                                              \
    _Pragma("unroll") for (int r = 0; r < 4; ++r)                             \
        pm[r] = fmaxf(sa[0][r], sa[1][r]);                                    \
    _Pragma("unroll") for (int mask = 1; mask <= 8; mask <<= 1)               \
      _Pragma("unroll") for (int r = 0; r < 4; ++r)                           \
        pm[r] = fmaxf(pm[r], __shfl_xor(pm[r], mask));                        \
    bool rb = false;                                                          \
    _Pragma("unroll") for (int r = 0; r < 4; ++r) rb |= (pm[r] > mrun[r] + 4.f); \
    if (__any(rb)) {                                                          \
      _Pragma("unroll") for (int r = 0; r < 4; ++r) {                         \
        float nm = (pm[r] > mrun[r] + 4.f) ? pm[r] : mrun[r];                 \
        float c_ = __expf(mrun[r] - nm);                                      \
        lsum[r] *= c_;                                                        \
        _Pragma("unroll") for (int c = 0; c < 4; ++c) oacc[c][r] *= c_;       \
        mrun[r] = nm;                                                         \
      }                                                                       \
    }                                                                         \
    float p0[4], p1[4];                                                       \
    _Pragma("unroll") for (int r = 0; r < 4; ++r) {                           \
      p0[r] = __expf(sa[0][r] - mrun[r]);                                     \
      p1[r] = __expf(sa[1][r] - mrun[r]);                                     \
      lsum[r] += p0[r] + p1[r];                                               \
    }                                                                         \
    _Pragma("unroll") for (int r = 0; r < 4; ++r) {                           \
      int row = hi4 * 4 + r;                                                  \
      myp[row * 40 + lo16] = (short)f2bf(p0[r]);                              \
      myp[row * 40 + 16 + lo16] = (short)f2bf(p1[r]);                         \
    }                                                                         \
    pa = *(const bfrag*)(myp + lo16 * 40 + hi4 * 8);                          \
  } while (0)

  auto step = [&](int buf) {
    const char* kh = (const char*)skh[buf];
    const char* kl = (const char*)skl[buf];
    f32x4 saA[2], saB[2];
#pragma unroll
    for (int t = 0; t < 2; ++t) {
      int jr = 16 * t + lo16;
      int sw = (jr & 7) << 4;
      const char* rowh = kh + jr * 128;
      const char* rowl = kl + jr * 128;
      bfrag kf0 = *(const bfrag*)(rowh + ((hi4 * 16) ^ sw));
      bfrag kf1 = *(const bfrag*)(rowh + ((64 + hi4 * 16) ^ sw));
      bfrag kg0 = *(const bfrag*)(rowl + ((hi4 * 16) ^ sw));
      bfrag kg1 = *(const bfrag*)(rowl + ((64 + hi4 * 16) ^ sw));
      f32x4 a = z;
      a = MFMA(qh0A, kf0, a);
      a = MFMA(qh1A, kf1, a);
      a = MFMA(qh0A, kg0, a);
      a = MFMA(qh1A, kg1, a);
      a = MFMA(ql0A, kf0, a);
      a = MFMA(ql1A, kf1, a);
      saA[t] = a;
      f32x4 b = z;
      b = MFMA(qh0B, kf0, b);
      b = MFMA(qh1B, kf1, b);
      b = MFMA(qh0B, kg0, b);
      b = MFMA(qh1B, kg1, b);
      b = MFMA(ql0B, kf0, b);
      b = MFMA(ql1B, kf1, b);
      saB[t] = b;
    }
    bfrag paA, paB;
    SMAX(saA, mrunA, lsumA, oaccA, mypA, paA);
    SMAX(saB, mrunB, lsumB, oaccB, mypB, paB);
    const char* vh = (const char*)svh[buf];
    const char* vl = (const char*)svl[buf];
#pragma unroll
    for (int c = 0; c < 4; ++c) {
      int dv = 16 * c + lo16;
      int svw = ((dv >> 1) & 3) << 4;
      bfrag vhf = *(const bfrag*)(vh + dv * 64 + ((hi4 * 16) ^ svw));
      bfrag vlf = *(const bfrag*)(vl + dv * 64 + ((hi4 * 16) ^ svw));
      oaccA[c] = MFMA(paA, vhf, oaccA[c]);
      oaccA[c] = MFMA(paA, vlf, oaccA[c]);
      oaccB[c] = MFMA(paB, vhf, oaccB[c]);
      oaccB[c] = MFMA(paB, vlf, oaccB[c]);
    }
  };

  STAGE(0, 0);
  STAGE(1, 1);
  for (int s = 0; s < NS - 1; ++s) {
    const int buf = s & 1;
    // own 4 loads for step s complete; step s+1's 4 stay in flight
    asm volatile("s_waitcnt vmcnt(4)" ::: "memory");
    __builtin_amdgcn_s_barrier();
    __builtin_amdgcn_sched_barrier(0);
    step(buf);
    __builtin_amdgcn_sched_barrier(0);
    __builtin_amdgcn_s_barrier();
    if (s + 2 < NS) STAGE(buf, s + 2);
  }
  // peeled last step: only its own 4 loads remain
  asm volatile("s_waitcnt vmcnt(0)" ::: "memory");
  __builtin_amdgcn_s_barrier();
  __builtin_amdgcn_sched_barrier(0);
  step((NS - 1) & 1);
#undef STAGE
#undef SMAX

  // reduce row sums across the 16 column-lanes
#pragma unroll
  for (int mask = 1; mask <= 8; mask <<= 1)
#pragma unroll
    for (int r = 0; r < 4; ++r) {
      lsumA[r] += __shfl_xor(lsumA[r], mask);
      lsumB[r] += __shfl_xor(lsumB[r], mask);
    }
  // store partials
#pragma unroll
  for (int c = 0; c < 4; ++c)
#pragma unroll
    for (int r = 0; r < 4; ++r) {
      Opart[((size_t)blockIdx.y * NN + q0 + hi4 * 4 + r) * 64 + 16 * c + lo16] = oaccA[c][r];
      Opart[((size_t)blockIdx.y * NN + q0 + 16 + hi4 * 4 + r) * 64 + 16 * c + lo16] = oaccB[c][r];
    }
  if (lo16 == 0) {
#pragma unroll
    for (int r = 0; r < 4; ++r) {
      mpart[blockIdx.y * NN + q0 + hi4 * 4 + r] = mrunA[r];
      lpart[blockIdx.y * NN + q0 + hi4 * 4 + r] = lsumA[r];
      mpart[blockIdx.y * NN + q0 + 16 + hi4 * 4 + r] = mrunB[r];
      lpart[blockIdx.y * NN + q0 + 16 + hi4 * 4 + r] = lsumB[r];
    }
  }
}

// combine partials -> o hi/lo bf16
__global__ void k_comb(const float* __restrict__ Opart,
                       const float* __restrict__ mpart,
                       const float* __restrict__ lpart,
                       short* __restrict__ Ohi, short* __restrict__ Olo) {
  int row = blockIdx.x * 4 + (threadIdx.x >> 6);
  int d = threadIdx.x & 63;
  float M = -1e30f;
  for (int i = 0; i < NCH; ++i) M = fmaxf(M, mpart[i * NN + row]);
  float L = 0.f, acc = 0.f;
  for (int i = 0; i < NCH; ++i) {
    float w = __expf(mpart[i * NN + row] - M);
    L += w * lpart[i * NN + row];
    acc += w * Opart[((size_t)i * NN + row) * 64 + d];
  }
  float o = acc / L;
  unsigned short h = f2bf(o);
  Ohi[(size_t)row * 64 + d] = (short)h;
  Olo[(size_t)row * 64 + d] = (short)f2bf(o - bf2f(h));
}

// ---------------- logits = o1 @ o2^T via bf16x3 MFMA, B-frag ping-pong prefetch ----------------

__global__ __launch_bounds__(256) void k_outer(const short* __restrict__ o1hi,
                                               const short* __restrict__ o1lo,
                                               const short* __restrict__ o2hi,
                                               const short* __restrict__ o2lo,
                                               float* __restrict__ out) {
  int wave = threadIdx.x >> 6, lane = threadIdx.x & 63;
  int lo16 = lane & 15, hi4 = lane >> 4;
  int i0 = blockIdx.x * 64 + wave * 16;
  const bfrag* aph = (const bfrag*)(o1hi + (size_t)(i0 + lo16) * 64 + hi4 * 8);
  const bfrag* apl = (const bfrag*)(o1lo + (size_t)(i0 + lo16) * 64 + hi4 * 8);
  bfrag ah0 = aph[0], ah1 = aph[4];
  bfrag al0 = apl[0], al1 = apl[4];
  f32x4 z = {0.f, 0.f, 0.f, 0.f};
  int jbase = blockIdx.y * (NN / 16);

#define LOADB(JV, BH0, BH1, BL0, BL1)                                        \
  do {                                                                       \
    const bfrag* bph = (const bfrag*)(o2hi + (size_t)((JV) + lo16) * 64 + hi4 * 8); \
    const bfrag* bpl = (const bfrag*)(o2lo + (size_t)((JV) + lo16) * 64 + hi4 * 8); \
    BH0 = bph[0]; BH1 = bph[4]; BL0 = bpl[0]; BL1 = bpl[4];                  \
  } while (0)

#define COMP(JV, BH0, BH1, BL0, BL1)                                  \
  do {                                                                \
    f32x4 acc = z;                                                    \
    acc = MFMA(ah0, BH0, acc);                                        \
    acc = MFMA(ah1, BH1, acc);                                        \
    acc = MFMA(ah0, BL0, acc);                                        \
    acc = MFMA(ah1, BL1, acc);                                        \
    acc = MFMA(al0, BH0, acc);                                        \
    acc = MFMA(al1, BH1, acc);                                        \
    _Pragma("unroll")                                                 \
    for (int r = 0; r < 4; ++r)                                       \
      out[(size_t)(i0 + hi4 * 4 + r) * NN + (JV) + lo16] = acc[r];    \
  } while (0)

  bfrag pah0, pah1, pal0, pal1, pbh0, pbh1, pbl0, pbl1;
  LOADB(jbase, pah0, pah1, pal0, pal1);
  for (int jt = 0; jt < NN / 16 / 16; jt += 2) {
    int ja = jbase + jt * 16;
    LOADB(ja + 16, pbh0, pbh1, pbl0, pbl1);
    COMP(ja, pah0, pah1, pal0, pal1);
    if (jt + 2 < NN / 16 / 16) LOADB(ja + 32, pah0, pah1, pal0, pal1);
    COMP(ja + 16, pbh0, pbh1, pbl0, pbl1);
  }
#undef LOADB
#undef COMP
}

// ---------------- launch ----------------

extern "C" void kernel_launch(void* const* d_in, const int* in_sizes, int n_in,
                              void* d_out, int out_size, void* d_ws, size_t ws_size,
                              hipStream_t stream) {
  const int* g1 = (const int*)d_in[0];
  const int* g2 = (const int*)d_in[1];
  const float* x1 = (const float*)d_in[2];
  const float* x2 = (const float*)d_in[3];
  const float* W11 = (const float*)d_in[4];
  const float* b11 = (const float*)d_in[5];
  const float* W12 = (const float*)d_in[6];
  const float* b12 = (const float*)d_in[7];
  const float* W21 = (const float*)d_in[8];
  const float* b21 = (const float*)d_in[9];
  const float* W22 = (const float*)d_in[10];
  const float* b22 = (const float*)d_in[11];
  const float* q1 = (const float*)d_in[12];
  const float* k1 = (const float*)d_in[13];
  const float* v1 = (const float*)d_in[14];
  const float* q2 = (const float*)d_in[15];
  const float* k2 = (const float*)d_in[16];
  const float* v2 = (const float*)d_in[17];

  // d_out (256 MB) is scratch for everything that dies before k_outer.
  char* ob = (char*)d_out;
  const size_t MB = 1u << 20;
  int* srcl1 = (int*)(ob + 0 * MB);
  int* srcl2 = (int*)(ob + 1 * MB);
  char* small = ob + 2 * MB;
  int* ideg1 = (int*)(small);
  int* ideg2 = (int*)(small + (32u << 10));
  int* off1 = (int*)(small + (64u << 10));
  int* off2 = (int*)(small + (128u << 10));
  int* cur1 = (int*)(small + (192u << 10));
  int* cur2 = (int*)(small + (256u << 10));
  float* dinv1 = (float*)(small + (320u << 10));
  float* dinv2 = (float*)(small + (384u << 10));
  short* whi = (short*)(ob + 3 * MB);            // 240KB
  short* wlo = (short*)(ob + 3 * MB + (512u << 10));
  short* a1hi = (short*)(ob + 4 * MB);           // 2MB each
  short* a1lo = (short*)(ob + 6 * MB);
  short* a2hi = (short*)(ob + 8 * MB);
  short* a2lo = (short*)(ob + 10 * MB);
  short* h1hi = (short*)(ob + 12 * MB);          // 4MB each
  short* h1lo = (short*)(ob + 16 * MB);
  short* h2hi = (short*)(ob + 20 * MB);
  short* h2lo = (short*)(ob + 24 * MB);
  float* tbuf1 = (float*)(ob + 28 * MB);         // 2MB each
  float* tbuf2 = (float*)(ob + 30 * MB);
  short* g1hi = (short*)(ob + 32 * MB);          // 1MB each
  short* g1lo = (short*)(ob + 33 * MB);
  short* g2hi = (short*)(ob + 34 * MB);
  short* g2lo = (short*)(ob + 35 * MB);
  short* Qhi = (short*)(ob + 36 * MB);
  short* Qlo = (short*)(ob + 37 * MB);
  short* Khi = (short*)(ob + 38 * MB);
  short* Klo = (short*)(ob + 39 * MB);
  short* Vthi = (short*)(ob + 40 * MB);
  short* Vtlo = (short*)(ob + 41 * MB);
  float* Opart = (float*)(ob + 42 * MB);         // 16MB
  float* mpart = (float*)(ob + 58 * MB);
  float* lpart = (float*)(ob + 58 * MB + (256u << 10));
  // d_ws: persists into k_outer
  short* o1hi = (short*)d_ws;
  short* o1lo = (short*)((char*)d_ws + 1 * MB);
  short* o2hi = (short*)((char*)d_ws + 2 * MB);
  short* o2lo = (short*)((char*)d_ws + 3 * MB);

  hipMemsetAsync(ideg1, 0, 64u << 10, stream);  // covers ideg1+ideg2
  k_count2<<<dim3(1024, 2), 256, 0, stream>>>(g1 + NE, g2 + NE, ideg1, ideg2);
  k_scan2<<<2, 1024, 0, stream>>>(ideg1, off1, cur1, dinv1, ideg2, off2, cur2, dinv2);
  k_fill2<<<dim3(1024, 2), 256, 0, stream>>>(g1, g1 + NE, cur1, srcl1,
                                             g2, g2 + NE, cur2, srcl2);
  k_split_w<<<dim3(128, 10), 256, 0, stream>>>(W11, W21, W12, W22, q1, k1, v1,
                                               q2, k2, v2, whi, wlo);

  // GCN (both branches fused per stage)
  k_agg1d<<<dim3(2048, 2), 256, 0, stream>>>(x1, x2, off1, srcl1, dinv1,
                                             off2, srcl2, dinv2,
                                             a1hi, a1lo, a2hi, a2lo);
  k_gemmL1<<<dim3(512, 4, 2), 64, 0, stream>>>(a1hi, a1lo, a2hi, a2lo, whi, wlo,
                                               b11, b21, h1hi, h1lo, h2hi, h2lo);
  k_gemmL2<<<dim3(512, 2), 64, 0, stream>>>(h1hi, h1lo, h2hi, h2lo, whi, wlo,
                                            tbuf1, tbuf2);
  k_agg2d<<<dim3(2048, 2), 256, 0, stream>>>(tbuf1, tbuf2, off1, srcl1, dinv1,
                                             off2, srcl2, dinv2, b12, b22,
                                             g1hi, g1lo, g2hi, g2lo);

  // cross attention 1: Q=g1@q1, K=g2@k1, V=g1@v1 -> o1
  k_qkv<<<dim3(512, 3), 64, 0, stream>>>(g1hi, g1lo, g2hi, g2lo, g1hi, g1lo,
                                         whi, wlo, 98304, 102400, 106496,
                                         Qhi, Qlo, Khi, Klo, Vthi, Vtlo);
  k_attn_v5<<<dim3(64, NCH), 256, 0, stream>>>(Qhi, Qlo, Khi, Klo, Vthi, Vtlo,
                                               Opart, mpart, lpart);
  k_comb<<<2048, 256, 0, stream>>>(Opart, mpart, lpart, o1hi, o1lo);

  // cross attention 2: Q=g2@q2, K=o1@k2, V=g2@v2 -> o2
  k_qkv<<<dim3(512, 3), 64, 0, stream>>>(g2hi, g2lo, o1hi, o1lo, g2hi, g2lo,
                                         whi, wlo, 110592, 114688, 118784,
                                         Qhi, Qlo, Khi, Klo, Vthi, Vtlo);
  k_attn_v5<<<dim3(64, NCH), 256, 0, stream>>>(Qhi, Qlo, Khi, Klo, Vthi, Vtlo,
                                               Opart, mpart, lpart);
  k_comb<<<2048, 256, 0, stream>>>(Opart, mpart, lpart, o2hi, o2lo);

  // logits = o1 @ o2^T -> d_out (overwrites all scratch)
  k_outer<<<dim3(128, 16), 256, 0, stream>>>(o1hi, o1lo, o2hi, o2lo, (float*)d_out);

  (void)in_sizes; (void)n_in; (void)out_size; (void)ws_size;
}

// Round 7
// 684.768 us; speedup vs baseline: 1.0589x; 1.0589x over previous
//
#include <hip/hip_runtime.h>
#include <math.h>

static constexpr int NN = 8192;      // nodes
static constexpr int NE = 262144;    // edges
static constexpr int NCH = 8;        // K-chunks for flash partials
static constexpr int NS = (NN / NCH) / 32;  // 32 steps per chunk

typedef short bfrag __attribute__((ext_vector_type(8)));   // 8 bf16 (A/B frag)
typedef float f32x4 __attribute__((ext_vector_type(4)));   // C/D frag

#define MFMA(a, b, c) __builtin_amdgcn_mfma_f32_16x16x32_bf16((a), (b), (c), 0, 0, 0)
#define CVTPK(d, a, b) \
  asm("v_cvt_pk_bf16_f32 %0, %1, %2" : "=v"(d) : "v"(a), "v"(b))

__device__ __forceinline__ unsigned short f2bf(float x) {
  union { float f; unsigned u; } v; v.f = x;
  unsigned r = v.u + 0x7fffu + ((v.u >> 16) & 1u);  // RNE
  return (unsigned short)(r >> 16);
}
__device__ __forceinline__ float bf2f(unsigned short h) {
  union { unsigned u; float f; } v; v.u = ((unsigned)h) << 16;
  return v.f;
}
__device__ __forceinline__ float bflo(unsigned u) {  // low bf16 of packed pair
  union { unsigned x; float f; } v; v.x = u << 16; return v.f;
}
__device__ __forceinline__ float bfhi(unsigned u) {  // high bf16 of packed pair
  union { unsigned x; float f; } v; v.x = u & 0xffff0000u; return v.f;
}

__device__ __forceinline__ void gll16(const void* g, void* l) {
  __builtin_amdgcn_global_load_lds(
      (const __attribute__((address_space(1))) unsigned*)g,
      (__attribute__((address_space(3))) unsigned*)l, 16, 0, 0);
}

// ---------------- graph prep ----------------

__global__ void k_count2(const int* __restrict__ d1, const int* __restrict__ d2,
                         int* __restrict__ i1, int* __restrict__ i2) {
  int t = blockIdx.x * 256 + threadIdx.x;
  const int* d = blockIdx.y ? d2 : d1;
  int* ii = blockIdx.y ? i2 : i1;
  if (t < NE) atomicAdd(&ii[d[t]], 1);
}

// shfl-based block scan
__global__ void k_scan2(const int* __restrict__ ideg1, int* __restrict__ off1,
                        int* __restrict__ cur1, float* __restrict__ dinv1,
                        const int* __restrict__ ideg2, int* __restrict__ off2,
                        int* __restrict__ cur2, float* __restrict__ dinv2) {
  const int* indeg = blockIdx.x ? ideg2 : ideg1;
  int* off = blockIdx.x ? off2 : off1;
  int* cur = blockIdx.x ? cur2 : cur1;
  float* dinv = blockIdx.x ? dinv2 : dinv1;
  __shared__ int wsum[16];
  int t = threadIdx.x, lane = t & 63, wv = t >> 6;
  int carry = 0;
  for (int base = 0; base < NN; base += 1024) {
    int v = indeg[base + t];
    int sc = v;
#pragma unroll
    for (int d = 1; d < 64; d <<= 1) {
      int o = __shfl_up(sc, d);
      if (lane >= d) sc += o;
    }
    if (lane == 63) wsum[wv] = sc;
    __syncthreads();
    if (t < 16) {
      int w = wsum[t];
#pragma unroll
      for (int d = 1; d < 16; d <<= 1) {
        int o = __shfl_up(w, d);
        if (t >= d) w += o;
      }
      wsum[t] = w;
    }
    __syncthreads();
    int excl = carry + (wv ? wsum[wv - 1] : 0) + sc - v;
    off[base + t] = excl;
    cur[base + t] = excl;
    dinv[base + t] = 1.0f / sqrtf((float)(v + 1));  // +1 self loop
    carry += wsum[15];
    __syncthreads();
  }
  if (t == 0) off[NN] = carry;
}

__global__ void k_fill2(const int* __restrict__ s1, const int* __restrict__ d1,
                        int* __restrict__ c1, int* __restrict__ l1,
                        const int* __restrict__ s2, const int* __restrict__ d2,
                        int* __restrict__ c2, int* __restrict__ l2) {
  int t = blockIdx.x * 256 + threadIdx.x;
  const int* src = blockIdx.y ? s2 : s1;
  const int* dst = blockIdx.y ? d2 : d1;
  int* cur = blockIdx.y ? c2 : c1;
  int* out = blockIdx.y ? l2 : l1;
  if (t < NE) {
    int d = dst[t];
    int slot = atomicAdd(&cur[d], 1);
    out[slot] = src[t];
  }
}

// ---------------- weight transpose + split (all 10 matrices, one launch) ----------------

__global__ void k_split_w(const float* W11, const float* W21, const float* W12,
                          const float* W22, const float* q1, const float* k1,
                          const float* v1, const float* q2, const float* k2,
                          const float* v2, short* __restrict__ whi,
                          short* __restrict__ wlo) {
  int y = blockIdx.y;
  const float* src; int R, C, base;
  if (y == 0)      { src = W11; R = 128; C = 256; base = 0; }
  else if (y == 1) { src = W21; R = 128; C = 256; base = 32768; }
  else if (y == 2) { src = W12; R = 256; C = 64;  base = 65536; }
  else if (y == 3) { src = W22; R = 256; C = 64;  base = 81920; }
  else if (y == 4) { src = q1;  R = 64;  C = 64;  base = 98304; }
  else if (y == 5) { src = k1;  R = 64;  C = 64;  base = 102400; }
  else if (y == 6) { src = v1;  R = 64;  C = 64;  base = 106496; }
  else if (y == 7) { src = q2;  R = 64;  C = 64;  base = 110592; }
  else if (y == 8) { src = k2;  R = 64;  C = 64;  base = 114688; }
  else             { src = v2;  R = 64;  C = 64;  base = 118784; }
  int idx = blockIdx.x * 256 + threadIdx.x;
  if (idx >= R * C) return;
  int r = idx / C, c = idx % C;
  float x = src[idx];
  unsigned short h = f2bf(x);
  whi[base + c * R + r] = (short)h;
  wlo[base + c * R + r] = (short)f2bf(x - bf2f(h));
}

// ---------------- layer-1 aggregation on raw x (D=128), wave per node, both branches ----------------

__global__ __launch_bounds__(256) void k_agg1d(
    const float* __restrict__ x1, const float* __restrict__ x2,
    const int* __restrict__ off1, const int* __restrict__ srcl1,
    const float* __restrict__ dinv1, const int* __restrict__ off2,
    const int* __restrict__ srcl2, const float* __restrict__ dinv2,
    short* __restrict__ a1hi, short* __restrict__ a1lo,
    short* __restrict__ a2hi, short* __restrict__ a2lo) {
  int br = blockIdx.y;
  const float* x = br ? x2 : x1;
  const int* off = br ? off2 : off1;
  const int* srcl = br ? srcl2 : srcl1;
  const float* dinv = br ? dinv2 : dinv1;
  short* ahi = br ? a2hi : a1hi;
  short* alo = br ? a2lo : a1lo;
  int wave = threadIdx.x >> 6, lane = threadIdx.x & 63;
  int node = blockIdx.x * 4 + wave;
  float dn = dinv[node];
  const float2* xr = (const float2*)x;
  float ax, ay;
  { float2 v = xr[(size_t)node * 64 + lane]; ax = dn * v.x; ay = dn * v.y; }
  int p = off[node], e = off[node + 1];
  for (; p + 3 < e; p += 4) {
    int s0 = srcl[p], s1 = srcl[p + 1], s2 = srcl[p + 2], s3 = srcl[p + 3];
    float w0 = dinv[s0], w1 = dinv[s1], w2 = dinv[s2], w3 = dinv[s3];
    float2 v0 = xr[(size_t)s0 * 64 + lane], v1 = xr[(size_t)s1 * 64 + lane];
    float2 v2 = xr[(size_t)s2 * 64 + lane], v3 = xr[(size_t)s3 * 64 + lane];
    ax += w0 * v0.x + w1 * v1.x + w2 * v2.x + w3 * v3.x;
    ay += w0 * v0.y + w1 * v1.y + w2 * v2.y + w3 * v3.y;
  }
  for (; p < e; ++p) {
    int s = srcl[p];
    float w = dinv[s];
    float2 v = xr[(size_t)s * 64 + lane];
    ax += w * v.x; ay += w * v.y;
  }
  float ox = dn * ax, oy = dn * ay;
  unsigned short hx = f2bf(ox), hy = f2bf(oy);
  int o = node * 128 + lane * 2;
  *(short2*)(ahi + o) = make_short2((short)hx, (short)hy);
  *(short2*)(alo + o) = make_short2((short)f2bf(ox - bf2f(hx)),
                                    (short)f2bf(oy - bf2f(hy)));
}

// ---------------- layer-2 aggregation (D=64) + bias, wave per node, both branches ----------------

__global__ __launch_bounds__(256) void k_agg2d(
    const float* __restrict__ t1, const float* __restrict__ t2,
    const int* __restrict__ off1, const int* __restrict__ srcl1,
    const float* __restrict__ dinv1, const int* __restrict__ off2,
    const int* __restrict__ srcl2, const float* __restrict__ dinv2,
    const float* __restrict__ b12, const float* __restrict__ b22,
    short* __restrict__ g1hi, short* __restrict__ g1lo,
    short* __restrict__ g2hi, short* __restrict__ g2lo) {
  int br = blockIdx.y;
  const float* t = br ? t2 : t1;
  const int* off = br ? off2 : off1;
  const int* srcl = br ? srcl2 : srcl1;
  const float* dinv = br ? dinv2 : dinv1;
  const float* bias = br ? b22 : b12;
  short* ghi = br ? g2hi : g1hi;
  short* glo = br ? g2lo : g1lo;
  int wave = threadIdx.x >> 6, lane = threadIdx.x & 63;
  int node = blockIdx.x * 4 + wave;
  float dn = dinv[node];
  float acc = dn * t[(size_t)node * 64 + lane];
  int p = off[node], e = off[node + 1];
  for (; p + 3 < e; p += 4) {
    int s0 = srcl[p], s1 = srcl[p + 1], s2 = srcl[p + 2], s3 = srcl[p + 3];
    float w0 = dinv[s0], w1 = dinv[s1], w2 = dinv[s2], w3 = dinv[s3];
    acc += w0 * t[(size_t)s0 * 64 + lane] + w1 * t[(size_t)s1 * 64 + lane] +
           w2 * t[(size_t)s2 * 64 + lane] + w3 * t[(size_t)s3 * 64 + lane];
  }
  for (; p < e; ++p) {
    int s = srcl[p];
    acc += dinv[s] * t[(size_t)s * 64 + lane];
  }
  float o = dn * acc + bias[lane];
  unsigned short h = f2bf(o);
  ghi[(size_t)node * 64 + lane] = (short)h;
  glo[(size_t)node * 64 + lane] = (short)f2bf(o - bf2f(h));
}

// ---------------- GCN layer-1 GEMM (K=128, N=256, bias+relu, hl out), both branches ----------------

__global__ __launch_bounds__(64) void k_gemmL1(
    const short* __restrict__ a1hi, const short* __restrict__ a1lo,
    const short* __restrict__ a2hi, const short* __restrict__ a2lo,
    const short* __restrict__ whi, const short* __restrict__ wlo,
    const float* __restrict__ b11, const float* __restrict__ b21,
    short* __restrict__ h1hi, short* __restrict__ h1lo,
    short* __restrict__ h2hi, short* __restrict__ h2lo) {
  int br = blockIdx.z;
  const short* Ahi = br ? a2hi : a1hi;
  const short* Alo = br ? a2lo : a1lo;
  const short* Bh = whi + (br ? 32768 : 0);
  const short* Bl = wlo + (br ? 32768 : 0);
  const float* bias = br ? b21 : b11;
  short* Chi = br ? h2hi : h1hi;
  short* Clo = br ? h2lo : h1lo;
  int lane = threadIdx.x;
  int lo16 = lane & 15, hi4 = lane >> 4;
  int r0 = blockIdx.x * 16;
  int c0 = blockIdx.y * 64;
  bfrag ah[4], al[4];
  const char* abh = (const char*)Ahi + ((size_t)(r0 + lo16) * 128 + hi4 * 8) * 2;
  const char* abl = (const char*)Alo + ((size_t)(r0 + lo16) * 128 + hi4 * 8) * 2;
#pragma unroll
  for (int ks = 0; ks < 4; ++ks) {
    ah[ks] = *(const bfrag*)(abh + ks * 64);
    al[ks] = *(const bfrag*)(abl + ks * 64);
  }
  f32x4 z = {0.f, 0.f, 0.f, 0.f};
  f32x4 acc[4] = {z, z, z, z};
#pragma unroll
  for (int c = 0; c < 4; ++c) {
    const char* bbh = (const char*)Bh + ((size_t)(c0 + c * 16 + lo16) * 128 + hi4 * 8) * 2;
    const char* bbl = (const char*)Bl + ((size_t)(c0 + c * 16 + lo16) * 128 + hi4 * 8) * 2;
#pragma unroll
    for (int ks = 0; ks < 4; ++ks) {
      bfrag bh = *(const bfrag*)(bbh + ks * 64);
      bfrag bl = *(const bfrag*)(bbl + ks * 64);
      acc[c] = MFMA(ah[ks], bh, acc[c]);
      acc[c] = MFMA(ah[ks], bl, acc[c]);
      acc[c] = MFMA(al[ks], bh, acc[c]);
    }
  }
#pragma unroll
  for (int c = 0; c < 4; ++c) {
    int col = c0 + c * 16 + lo16;
    float bv = bias[col];
#pragma unroll
    for (int r = 0; r < 4; ++r) {
      int row = r0 + hi4 * 4 + r;
      float v = fmaxf(acc[c][r] + bv, 0.f);
      unsigned short h = f2bf(v);
      Chi[(size_t)row * 256 + col] = (short)h;
      Clo[(size_t)row * 256 + col] = (short)f2bf(v - bf2f(h));
    }
  }
}

// ---------------- GCN layer-2 GEMM (K=256, N=64, f32 out), both branches ----------------

__global__ __launch_bounds__(64) void k_gemmL2(
    const short* __restrict__ h1hi, const short* __restrict__ h1lo,
    const short* __restrict__ h2hi, const short* __restrict__ h2lo,
    const short* __restrict__ whi, const short* __restrict__ wlo,
    float* __restrict__ t1, float* __restrict__ t2) {
  int br = blockIdx.y;
  const short* Ahi = br ? h2hi : h1hi;
  const short* Alo = br ? h2lo : h1lo;
  const short* Bh = whi + (br ? 81920 : 65536);
  const short* Bl = wlo + (br ? 81920 : 65536);
  float* Cf = br ? t2 : t1;
  int lane = threadIdx.x;
  int lo16 = lane & 15, hi4 = lane >> 4;
  int r0 = blockIdx.x * 16;
  bfrag ah[8], al[8];
  const char* abh = (const char*)Ahi + ((size_t)(r0 + lo16) * 256 + hi4 * 8) * 2;
  const char* abl = (const char*)Alo + ((size_t)(r0 + lo16) * 256 + hi4 * 8) * 2;
#pragma unroll
  for (int ks = 0; ks < 8; ++ks) {
    ah[ks] = *(const bfrag*)(abh + ks * 64);
    al[ks] = *(const bfrag*)(abl + ks * 64);
  }
  f32x4 z = {0.f, 0.f, 0.f, 0.f};
  f32x4 acc[4] = {z, z, z, z};
#pragma unroll
  for (int c = 0; c < 4; ++c) {
    const char* bbh = (const char*)Bh + ((size_t)(c * 16 + lo16) * 256 + hi4 * 8) * 2;
    const char* bbl = (const char*)Bl + ((size_t)(c * 16 + lo16) * 256 + hi4 * 8) * 2;
#pragma unroll
    for (int ks = 0; ks < 8; ++ks) {
      bfrag bh = *(const bfrag*)(bbh + ks * 64);
      bfrag bl = *(const bfrag*)(bbl + ks * 64);
      acc[c] = MFMA(ah[ks], bh, acc[c]);
      acc[c] = MFMA(ah[ks], bl, acc[c]);
      acc[c] = MFMA(al[ks], bh, acc[c]);
    }
  }
#pragma unroll
  for (int c = 0; c < 4; ++c) {
    int col = c * 16 + lo16;
#pragma unroll
    for (int r = 0; r < 4; ++r)
      Cf[(size_t)(r0 + hi4 * 4 + r) * 64 + col] = acc[c][r];
  }
}

// ---------------- QKV projections; V writes transposed hi/lo directly ----------------

__global__ __launch_bounds__(64) void k_qkv(
    const short* __restrict__ Aqhi, const short* __restrict__ Aqlo,
    const short* __restrict__ Akhi, const short* __restrict__ Aklo,
    const short* __restrict__ Avhi, const short* __restrict__ Avlo,
    const short* __restrict__ whi, const short* __restrict__ wlo,
    int bq, int bk, int bv,
    short* __restrict__ Qhi, short* __restrict__ Qlo,
    short* __restrict__ Khi, short* __restrict__ Klo,
    short* __restrict__ Vthi, short* __restrict__ Vtlo) {
  int y = blockIdx.y;
  const short *Ah, *Al;
  int boff;
  if (y == 0)      { Ah = Aqhi; Al = Aqlo; boff = bq; }
  else if (y == 1) { Ah = Akhi; Al = Aklo; boff = bk; }
  else             { Ah = Avhi; Al = Avlo; boff = bv; }
  const short* Bh = whi + boff;
  const short* Bl = wlo + boff;
  int lane = threadIdx.x;
  int lo16 = lane & 15, hi4 = lane >> 4;
  int r0 = blockIdx.x * 16;
  bfrag ah0, ah1, al0, al1;
  {
    const char* a = (const char*)(Ah + (size_t)(r0 + lo16) * 64 + hi4 * 8);
    const char* b = (const char*)(Al + (size_t)(r0 + lo16) * 64 + hi4 * 8);
    ah0 = *(const bfrag*)a; ah1 = *(const bfrag*)(a + 64);
    al0 = *(const bfrag*)b; al1 = *(const bfrag*)(b + 64);
  }
  f32x4 z = {0.f, 0.f, 0.f, 0.f};
  f32x4 acc[4] = {z, z, z, z};
#pragma unroll
  for (int c = 0; c < 4; ++c) {
    const char* bbh = (const char*)(Bh + (size_t)(c * 16 + lo16) * 64 + hi4 * 8);
    const char* bbl = (const char*)(Bl + (size_t)(c * 16 + lo16) * 64 + hi4 * 8);
    bfrag bh0 = *(const bfrag*)bbh, bh1 = *(const bfrag*)(bbh + 64);
    bfrag bl0 = *(const bfrag*)bbl, bl1 = *(const bfrag*)(bbl + 64);
    acc[c] = MFMA(ah0, bh0, acc[c]);
    acc[c] = MFMA(ah1, bh1, acc[c]);
    acc[c] = MFMA(ah0, bl0, acc[c]);
    acc[c] = MFMA(ah1, bl1, acc[c]);
    acc[c] = MFMA(al0, bh0, acc[c]);
    acc[c] = MFMA(al1, bh1, acc[c]);
  }
  if (y == 2) {
#pragma unroll
    for (int c = 0; c < 4; ++c) {
      int col = c * 16 + lo16;
      short4 vh, vl;
      float v0 = acc[c][0], v1 = acc[c][1], v2 = acc[c][2], v3 = acc[c][3];
      unsigned short h0 = f2bf(v0), h1 = f2bf(v1), h2 = f2bf(v2), h3 = f2bf(v3);
      vh = make_short4((short)h0, (short)h1, (short)h2, (short)h3);
      vl = make_short4((short)f2bf(v0 - bf2f(h0)), (short)f2bf(v1 - bf2f(h1)),
                       (short)f2bf(v2 - bf2f(h2)), (short)f2bf(v3 - bf2f(h3)));
      size_t o = (size_t)col * NN + r0 + hi4 * 4;
      *(short4*)(Vthi + o) = vh;
      *(short4*)(Vtlo + o) = vl;
    }
  } else {
    short* oh = (y == 0) ? Qhi : Khi;
    short* ol = (y == 0) ? Qlo : Klo;
#pragma unroll
    for (int c = 0; c < 4; ++c) {
      int col = c * 16 + lo16;
#pragma unroll
      for (int r = 0; r < 4; ++r) {
        int row = r0 + hi4 * 4 + r;
        float v = acc[c][r];
        unsigned short h = f2bf(v);
        oh[(size_t)row * 64 + col] = (short)h;
        ol[(size_t)row * 64 + col] = (short)f2bf(v - bf2f(h));
      }
    }
  }
}

// ---------------- MFMA flash attention v7 ----------------
// 4 waves x 32 Q rows; grid (NN/128, NCH=8); counted-vmcnt pipeline;
// cvt_pk P conversion with CONSISTENT lsum (rounded weights in both
// numerator and denominator -> first-order error cancellation); setprio.

__global__ __launch_bounds__(256) void k_attn_v7(
    const short* __restrict__ Qhi, const short* __restrict__ Qlo,
    const short* __restrict__ Khi_g, const short* __restrict__ Klo_g,
    const short* __restrict__ Vthi_g, const short* __restrict__ Vtlo_g,
    float* __restrict__ Opart, float* __restrict__ mpart, float* __restrict__ lpart) {
  __shared__ short skh[2][32 * 64], skl[2][32 * 64];
  __shared__ short svh[2][64 * 32], svl[2][64 * 32];
  __shared__ short plds[8][16 * 40];
  const int tid = threadIdx.x;
  const int wave = tid >> 6, lane = tid & 63;
  const int lo16 = lane & 15, hi4 = lane >> 4;
  const int q0 = blockIdx.x * 128 + wave * 32;
  const int j0 = blockIdx.y * (NN / NCH);
  short* mypA = plds[wave * 2];
  short* mypB = plds[wave * 2 + 1];

  const int krow = wave * 8 + (lane >> 3);
  const int kcbs = ((lane & 7) * 16) ^ ((krow & 7) << 4);
  const int vrow = wave * 16 + (lane >> 2);
  const int vcbs = ((lane & 3) * 16) ^ (((vrow >> 1) & 3) << 4);
  const char* gka = (const char*)Khi_g + (size_t)(j0 + krow) * 128 + kcbs;
  const char* gkb = (const char*)Klo_g + (size_t)(j0 + krow) * 128 + kcbs;
  const char* gva = (const char*)Vthi_g + (size_t)vrow * (NN * 2) + (size_t)j0 * 2 + vcbs;
  const char* gvb = (const char*)Vtlo_g + (size_t)vrow * (NN * 2) + (size_t)j0 * 2 + vcbs;

#define STAGE(buf, s)                                                \
  do {                                                               \
    gll16(gka + (size_t)(s) * 4096, (char*)skh[buf] + wave * 1024);  \
    gll16(gkb + (size_t)(s) * 4096, (char*)skl[buf] + wave * 1024);  \
    gll16(gva + (s) * 64, (char*)svh[buf] + wave * 1024);            \
    gll16(gvb + (s) * 64, (char*)svl[buf] + wave * 1024);            \
  } while (0)

  const bfrag* qphA = (const bfrag*)(Qhi + (size_t)(q0 + lo16) * 64 + hi4 * 8);
  const bfrag* qplA = (const bfrag*)(Qlo + (size_t)(q0 + lo16) * 64 + hi4 * 8);
  const bfrag* qphB = (const bfrag*)(Qhi + (size_t)(q0 + 16 + lo16) * 64 + hi4 * 8);
  const bfrag* qplB = (const bfrag*)(Qlo + (size_t)(q0 + 16 + lo16) * 64 + hi4 * 8);
  bfrag qh0A = qphA[0], qh1A = qphA[4], ql0A = qplA[0], ql1A = qplA[4];
  bfrag qh0B = qphB[0], qh1B = qphB[4], ql0B = qplB[0], ql1B = qplB[4];

  f32x4 z = {0.f, 0.f, 0.f, 0.f};
  f32x4 oaccA[4] = {z, z, z, z}, oaccB[4] = {z, z, z, z};
  float mrunA[4] = {-1e30f, -1e30f, -1e30f, -1e30f};
  float mrunB[4] = {-1e30f, -1e30f, -1e30f, -1e30f};
  float lsumA[4] = {0.f, 0.f, 0.f, 0.f}, lsumB[4] = {0.f, 0.f, 0.f, 0.f};

#define SMAX(sa, mrun, lsum, oacc, myp, pa)                                   \
  do {                                                                        \
    _Pragma("unroll") for (int t = 0; t < 2; ++t)                             \
      _Pragma("unroll") for (int r = 0; r < 4; ++r) {                         \
        float v = sa[t][r];                                                   \
        sa[t][r] = fmaxf(v, 0.01f * v);                                       \
      }                                                                       \
    float pm[4];                                                              \
    _Pragma("unroll") for (int r = 0; r < 4; ++r)                             \
        pm[r] = fmaxf(sa[0][r], sa[1][r]);                                    \
    _Pragma("unroll") for (int mask = 1; mask <= 8; mask <<= 1)               \
      _Pragma("unroll") for (int r = 0; r < 4; ++r)                           \
        pm[r] = fmaxf(pm[r], __shfl_xor(pm[r], mask));                        \
    bool rb = false;                                                          \
    _Pragma("unroll") for (int r = 0; r < 4; ++r) rb |= (pm[r] > mrun[r] + 4.f); \
    if (__any(rb)) {                                                          \
      _Pragma("unroll") for (int r = 0; r < 4; ++r) {                         \
        float nm = (pm[r] > mrun[r] + 4.f) ? pm[r] : mrun[r];                 \
        float c_ = __expf(mrun[r] - nm);                                      \
        lsum[r] *= c_;                                                        \
        _Pragma("unroll") for (int c = 0; c < 4; ++c) oacc[c][r] *= c_;       \
        mrun[r] = nm;                                                         \
      }                                                                       \
    }                                                                         \
    float p0[4], p1[4];                                                       \
    _Pragma("unroll") for (int r = 0; r < 4; ++r) {                           \
      p0[r] = __expf(sa[0][r] - mrun[r]);                                     \
      p1[r] = __expf(sa[1][r] - mrun[r]);                                     \
    }                                                                         \
    unsigned pq0, pq1, pq2, pq3;                                              \
    CVTPK(pq0, p0[0], p0[1]);                                                 \
    CVTPK(pq1, p0[2], p0[3]);                                                 \
    CVTPK(pq2, p1[0], p1[1]);                                                 \
    CVTPK(pq3, p1[2], p1[3]);                                                 \
    /* consistent denominator: accumulate the ROUNDED weights */              \
    lsum[0] += bflo(pq0) + bflo(pq2);                                         \
    lsum[1] += bfhi(pq0) + bfhi(pq2);                                         \
    lsum[2] += bflo(pq1) + bflo(pq3);                                         \
    lsum[3] += bfhi(pq1) + bfhi(pq3);                                         \
    {                                                                         \
      int rb_ = hi4 * 4;                                                      \
      myp[(rb_ + 0) * 40 + lo16] = (short)pq0;                                \
      myp[(rb_ + 1) * 40 + lo16] = (short)(pq0 >> 16);                        \
      myp[(rb_ + 2) * 40 + lo16] = (short)pq1;                                \
      myp[(rb_ + 3) * 40 + lo16] = (short)(pq1 >> 16);                        \
      myp[(rb_ + 0) * 40 + 16 + lo16] = (short)pq2;                           \
      myp[(rb_ + 1) * 40 + 16 + lo16] = (short)(pq2 >> 16);                   \
      myp[(rb_ + 2) * 40 + 16 + lo16] = (short)pq3;                           \
      myp[(rb_ + 3) * 40 + 16 + lo16] = (short)(pq3 >> 16);                   \
    }                                                                         \
    pa = *(const bfrag*)(myp + lo16 * 40 + hi4 * 8);                          \
  } while (0)

  auto step = [&](int buf) {
    const char* kh = (const char*)skh[buf];
    const char* kl = (const char*)skl[buf];
    f32x4 saA[2], saB[2];
    __builtin_amdgcn_s_setprio(1);
#pragma unroll
    for (int t = 0; t < 2; ++t) {
      int jr = 16 * t + lo16;
      int sw = (jr & 7) << 4;
      const char* rowh = kh + jr * 128;
      const char* rowl = kl + jr * 128;
      bfrag kf0 = *(const bfrag*)(rowh + ((hi4 * 16) ^ sw));
      bfrag kf1 = *(const bfrag*)(rowh + ((64 + hi4 * 16) ^ sw));
      bfrag kg0 = *(const bfrag*)(rowl + ((hi4 * 16) ^ sw));
      bfrag kg1 = *(const bfrag*)(rowl + ((64 + hi4 * 16) ^ sw));
      f32x4 a = z;
      a = MFMA(qh0A, kf0, a);
      a = MFMA(qh1A, kf1, a);
      a = MFMA(qh0A, kg0, a);
      a = MFMA(qh1A, kg1, a);
      a = MFMA(ql0A, kf0, a);
      a = MFMA(ql1A, kf1, a);
      saA[t] = a;
      f32x4 b = z;
      b = MFMA(qh0B, kf0, b);
      b = MFMA(qh1B, kf1, b);
      b = MFMA(qh0B, kg0, b);
      b = MFMA(qh1B, kg1, b);
      b = MFMA(ql0B, kf0, b);
      b = MFMA(ql1B, kf1, b);
      saB[t] = b;
    }
    __builtin_amdgcn_s_setprio(0);
    bfrag paA, paB;
    SMAX(saA, mrunA, lsumA, oaccA, mypA, paA);
    SMAX(saB, mrunB, lsumB, oaccB, mypB, paB);
    const char* vh = (const char*)svh[buf];
    const char* vl = (const char*)svl[buf];
    __builtin_amdgcn_s_setprio(1);
#pragma unroll
    for (int c = 0; c < 4; ++c) {
      int dv = 16 * c + lo16;
      int svw = ((dv >> 1) & 3) << 4;
      bfrag vhf = *(const bfrag*)(vh + dv * 64 + ((hi4 * 16) ^ svw));
      bfrag vlf = *(const bfrag*)(vl + dv * 64 + ((hi4 * 16) ^ svw));
      oaccA[c] = MFMA(paA, vhf, oaccA[c]);
      oaccA[c] = MFMA(paA, vlf, oaccA[c]);
      oaccB[c] = MFMA(paB, vhf, oaccB[c]);
      oaccB[c] = MFMA(paB, vlf, oaccB[c]);
    }
    __builtin_amdgcn_s_setprio(0);
  };

  STAGE(0, 0);
  STAGE(1, 1);
  for (int s = 0; s < NS - 1; ++s) {
    const int buf = s & 1;
    asm volatile("s_waitcnt vmcnt(4)" ::: "memory");
    __builtin_amdgcn_s_barrier();
    __builtin_amdgcn_sched_barrier(0);
    step(buf);
    __builtin_amdgcn_sched_barrier(0);
    __builtin_amdgcn_s_barrier();
    if (s + 2 < NS) STAGE(buf, s + 2);
  }
  asm volatile("s_waitcnt vmcnt(0)" ::: "memory");
  __builtin_amdgcn_s_barrier();
  __builtin_amdgcn_sched_barrier(0);
  step((NS - 1) & 1);
#undef STAGE
#undef SMAX

#pragma unroll
  for (int mask = 1; mask <= 8; mask <<= 1)
#pragma unroll
    for (int r = 0; r < 4; ++r) {
      lsumA[r] += __shfl_xor(lsumA[r], mask);
      lsumB[r] += __shfl_xor(lsumB[r], mask);
    }
#pragma unroll
  for (int c = 0; c < 4; ++c)
#pragma unroll
    for (int r = 0; r < 4; ++r) {
      Opart[((size_t)blockIdx.y * NN + q0 + hi4 * 4 + r) * 64 + 16 * c + lo16] = oaccA[c][r];
      Opart[((size_t)blockIdx.y * NN + q0 + 16 + hi4 * 4 + r) * 64 + 16 * c + lo16] = oaccB[c][r];
    }
  if (lo16 == 0) {
#pragma unroll
    for (int r = 0; r < 4; ++r) {
      mpart[blockIdx.y * NN + q0 + hi4 * 4 + r] = mrunA[r];
      lpart[blockIdx.y * NN + q0 + hi4 * 4 + r] = lsumA[r];
      mpart[blockIdx.y * NN + q0 + 16 + hi4 * 4 + r] = mrunB[r];
      lpart[blockIdx.y * NN + q0 + 16 + hi4 * 4 + r] = lsumB[r];
    }
  }
}

// combine partials -> o hi/lo bf16
__global__ void k_comb(const float* __restrict__ Opart,
                       const float* __restrict__ mpart,
                       const float* __restrict__ lpart,
                       short* __restrict__ Ohi, short* __restrict__ Olo) {
  int row = blockIdx.x * 4 + (threadIdx.x >> 6);
  int d = threadIdx.x & 63;
  float M = -1e30f;
  for (int i = 0; i < NCH; ++i) M = fmaxf(M, mpart[i * NN + row]);
  float L = 0.f, acc = 0.f;
  for (int i = 0; i < NCH; ++i) {
    float w = __expf(mpart[i * NN + row] - M);
    L += w * lpart[i * NN + row];
    acc += w * Opart[((size_t)i * NN + row) * 64 + d];
  }
  float o = acc / L;
  unsigned short h = f2bf(o);
  Ohi[(size_t)row * 64 + d] = (short)h;
  Olo[(size_t)row * 64 + d] = (short)f2bf(o - bf2f(h));
}

// ---------------- logits = o1 @ o2^T; 2 i-tiles/wave, B ping-pong ----------------

__global__ __launch_bounds__(256) void k_outer(const short* __restrict__ o1hi,
                                               const short* __restrict__ o1lo,
                                               const short* __restrict__ o2hi,
                                               const short* __restrict__ o2lo,
                                               float* __restrict__ out) {
  int wave = threadIdx.x >> 6, lane = threadIdx.x & 63;
  int lo16 = lane & 15, hi4 = lane >> 4;
  int i0 = blockIdx.x * 128 + wave * 32;
  const bfrag* aphA = (const bfrag*)(o1hi + (size_t)(i0 + lo16) * 64 + hi4 * 8);
  const bfrag* aplA = (const bfrag*)(o1lo + (size_t)(i0 + lo16) * 64 + hi4 * 8);
  const bfrag* aphB = (const bfrag*)(o1hi + (size_t)(i0 + 16 + lo16) * 64 + hi4 * 8);
  const bfrag* aplB = (const bfrag*)(o1lo + (size_t)(i0 + 16 + lo16) * 64 + hi4 * 8);
  bfrag ah0A = aphA[0], ah1A = aphA[4], al0A = aplA[0], al1A = aplA[4];
  bfrag ah0B = aphB[0], ah1B = aphB[4], al0B = aplB[0], al1B = aplB[4];
  f32x4 z = {0.f, 0.f, 0.f, 0.f};
  int jbase = blockIdx.y * (NN / 16);

#define LOADB(JV, BH0, BH1, BL0, BL1)                                        \
  do {                                                                       \
    const bfrag* bph = (const bfrag*)(o2hi + (size_t)((JV) + lo16) * 64 + hi4 * 8); \
    const bfrag* bpl = (const bfrag*)(o2lo + (size_t)((JV) + lo16) * 64 + hi4 * 8); \
    BH0 = bph[0]; BH1 = bph[4]; BL0 = bpl[0]; BL1 = bpl[4];                  \
  } while (0)

#define COMP(JV, BH0, BH1, BL0, BL1)                                  \
  do {                                                                \
    f32x4 accA = z, accB = z;                                         \
    accA = MFMA(ah0A, BH0, accA);                                     \
    accA = MFMA(ah1A, BH1, accA);                                     \
    accA = MFMA(ah0A, BL0, accA);                                     \
    accA = MFMA(ah1A, BL1, accA);                                     \
    accA = MFMA(al0A, BH0, accA);                                     \
    accA = MFMA(al1A, BH1, accA);                                     \
    accB = MFMA(ah0B, BH0, accB);                                     \
    accB = MFMA(ah1B, BH1, accB);                                     \
    accB = MFMA(ah0B, BL0, accB);                                     \
    accB = MFMA(ah1B, BL1, accB);                                     \
    accB = MFMA(al0B, BH0, accB);                                     \
    accB = MFMA(al1B, BH1, accB);                                     \
    _Pragma("unroll")                                                 \
    for (int r = 0; r < 4; ++r) {                                     \
      out[(size_t)(i0 + hi4 * 4 + r) * NN + (JV) + lo16] = accA[r];   \
      out[(size_t)(i0 + 16 + hi4 * 4 + r) * NN + (JV) + lo16] = accB[r]; \
    }                                                                 \
  } while (0)

  bfrag pah0, pah1, pal0, pal1, pbh0, pbh1, pbl0, pbl1;
  LOADB(jbase, pah0, pah1, pal0, pal1);
  for (int jt = 0; jt < NN / 16 / 16; jt += 2) {
    int ja = jbase + jt * 16;
    LOADB(ja + 16, pbh0, pbh1, pbl0, pbl1);
    COMP(ja, pah0, pah1, pal0, pal1);
    if (jt + 2 < NN / 16 / 16) LOADB(ja + 32, pah0, pah1, pal0, pal1);
    COMP(ja + 16, pbh0, pbh1, pbl0, pbl1);
  }
#undef LOADB
#undef COMP
}

// ---------------- launch ----------------

extern "C" void kernel_launch(void* const* d_in, const int* in_sizes, int n_in,
                              void* d_out, int out_size, void* d_ws, size_t ws_size,
                              hipStream_t stream) {
  const int* g1 = (const int*)d_in[0];
  const int* g2 = (const int*)d_in[1];
  const float* x1 = (const float*)d_in[2];
  const float* x2 = (const float*)d_in[3];
  const float* W11 = (const float*)d_in[4];
  const float* b11 = (const float*)d_in[5];
  const float* W12 = (const float*)d_in[6];
  const float* b12 = (const float*)d_in[7];
  const float* W21 = (const float*)d_in[8];
  const float* b21 = (const float*)d_in[9];
  const float* W22 = (const float*)d_in[10];
  const float* b22 = (const float*)d_in[11];
  const float* q1 = (const float*)d_in[12];
  const float* k1 = (const float*)d_in[13];
  const float* v1 = (const float*)d_in[14];
  const float* q2 = (const float*)d_in[15];
  const float* k2 = (const float*)d_in[16];
  const float* v2 = (const float*)d_in[17];

  char* ob = (char*)d_out;
  const size_t MB = 1u << 20;
  int* srcl1 = (int*)(ob + 0 * MB);
  int* srcl2 = (int*)(ob + 1 * MB);
  char* small = ob + 2 * MB;
  int* ideg1 = (int*)(small);
  int* ideg2 = (int*)(small + (32u << 10));
  int* off1 = (int*)(small + (64u << 10));
  int* off2 = (int*)(small + (128u << 10));
  int* cur1 = (int*)(small + (192u << 10));
  int* cur2 = (int*)(small + (256u << 10));
  float* dinv1 = (float*)(small + (320u << 10));
  float* dinv2 = (float*)(small + (384u << 10));
  short* whi = (short*)(ob + 3 * MB);
  short* wlo = (short*)(ob + 3 * MB + (512u << 10));
  short* a1hi = (short*)(ob + 4 * MB);
  short* a1lo = (short*)(ob + 6 * MB);
  short* a2hi = (short*)(ob + 8 * MB);
  short* a2lo = (short*)(ob + 10 * MB);
  short* h1hi = (short*)(ob + 12 * MB);
  short* h1lo = (short*)(ob + 16 * MB);
  short* h2hi = (short*)(ob + 20 * MB);
  short* h2lo = (short*)(ob + 24 * MB);
  float* tbuf1 = (float*)(ob + 28 * MB);
  float* tbuf2 = (float*)(ob + 30 * MB);
  short* g1hi = (short*)(ob + 32 * MB);
  short* g1lo = (short*)(ob + 33 * MB);
  short* g2hi = (short*)(ob + 34 * MB);
  short* g2lo = (short*)(ob + 35 * MB);
  short* Qhi = (short*)(ob + 36 * MB);
  short* Qlo = (short*)(ob + 37 * MB);
  short* Khi = (short*)(ob + 38 * MB);
  short* Klo = (short*)(ob + 39 * MB);
  short* Vthi = (short*)(ob + 40 * MB);
  short* Vtlo = (short*)(ob + 41 * MB);
  float* Opart = (float*)(ob + 42 * MB);         // 16MB (8 x 8192 x 64)
  float* mpart = (float*)(ob + 58 * MB);         // 256KB
  float* lpart = (float*)(ob + 58 * MB + (256u << 10));
  short* o1hi = (short*)d_ws;
  short* o1lo = (short*)((char*)d_ws + 1 * MB);
  short* o2hi = (short*)((char*)d_ws + 2 * MB);
  short* o2lo = (short*)((char*)d_ws + 3 * MB);

  hipMemsetAsync(ideg1, 0, 64u << 10, stream);
  k_count2<<<dim3(1024, 2), 256, 0, stream>>>(g1 + NE, g2 + NE, ideg1, ideg2);
  k_scan2<<<2, 1024, 0, stream>>>(ideg1, off1, cur1, dinv1, ideg2, off2, cur2, dinv2);
  k_fill2<<<dim3(1024, 2), 256, 0, stream>>>(g1, g1 + NE, cur1, srcl1,
                                             g2, g2 + NE, cur2, srcl2);
  k_split_w<<<dim3(128, 10), 256, 0, stream>>>(W11, W21, W12, W22, q1, k1, v1,
                                               q2, k2, v2, whi, wlo);

  k_agg1d<<<dim3(2048, 2), 256, 0, stream>>>(x1, x2, off1, srcl1, dinv1,
                                             off2, srcl2, dinv2,
                                             a1hi, a1lo, a2hi, a2lo);
  k_gemmL1<<<dim3(512, 4, 2), 64, 0, stream>>>(a1hi, a1lo, a2hi, a2lo, whi, wlo,
                                               b11, b21, h1hi, h1lo, h2hi, h2lo);
  k_gemmL2<<<dim3(512, 2), 64, 0, stream>>>(h1hi, h1lo, h2hi, h2lo, whi, wlo,
                                            tbuf1, tbuf2);
  k_agg2d<<<dim3(2048, 2), 256, 0, stream>>>(tbuf1, tbuf2, off1, srcl1, dinv1,
                                             off2, srcl2, dinv2, b12, b22,
                                             g1hi, g1lo, g2hi, g2lo);

  // cross attention 1: Q=g1@q1, K=g2@k1, V=g1@v1 -> o1
  k_qkv<<<dim3(512, 3), 64, 0, stream>>>(g1hi, g1lo, g2hi, g2lo, g1hi, g1lo,
                                         whi, wlo, 98304, 102400, 106496,
                                         Qhi, Qlo, Khi, Klo, Vthi, Vtlo);
  k_attn_v7<<<dim3(64, NCH), 256, 0, stream>>>(Qhi, Qlo, Khi, Klo, Vthi, Vtlo,
                                               Opart, mpart, lpart);
  k_comb<<<2048, 256, 0, stream>>>(Opart, mpart, lpart, o1hi, o1lo);

  // cross attention 2: Q=g2@q2, K=o1@k2, V=g2@v2 -> o2
  k_qkv<<<dim3(512, 3), 64, 0, stream>>>(g2hi, g2lo, o1hi, o1lo, g2hi, g2lo,
                                         whi, wlo, 110592, 114688, 118784,
                                         Qhi, Qlo, Khi, Klo, Vthi, Vtlo);
  k_attn_v7<<<dim3(64, NCH), 256, 0, stream>>>(Qhi, Qlo, Khi, Klo, Vthi, Vtlo,
                                               Opart, mpart, lpart);
  k_comb<<<2048, 256, 0, stream>>>(Opart, mpart, lpart, o2hi, o2lo);

  // logits = o1 @ o2^T -> d_out (overwrites all scratch)
  k_outer<<<dim3(64, 16), 256, 0, stream>>>(o1hi, o1lo, o2hi, o2lo, (float*)d_out);

  (void)in_sizes; (void)n_in; (void)out_size; (void)ws_size;
}

// Round 8
// 636.193 us; speedup vs baseline: 1.1398x; 1.0764x over previous
//
#include <hip/hip_runtime.h>
#include <math.h>

static constexpr int NN = 8192;      // nodes
static constexpr int NE = 262144;    // edges
static constexpr int NCH = 8;        // K-chunks for flash partials
static constexpr int NS = (NN / NCH) / 32;  // 32 steps per chunk

typedef short bfrag __attribute__((ext_vector_type(8)));   // 8 bf16 (A/B frag)
typedef float f32x4 __attribute__((ext_vector_type(4)));   // C/D frag

#define MFMA(a, b, c) __builtin_amdgcn_mfma_f32_16x16x32_bf16((a), (b), (c), 0, 0, 0)
#define CVTPK(d, a, b) \
  asm("v_cvt_pk_bf16_f32 %0, %1, %2" : "=v"(d) : "v"(a), "v"(b))

__device__ __forceinline__ unsigned short f2bf(float x) {
  union { float f; unsigned u; } v; v.f = x;
  unsigned r = v.u + 0x7fffu + ((v.u >> 16) & 1u);  // RNE
  return (unsigned short)(r >> 16);
}
__device__ __forceinline__ float bf2f(unsigned short h) {
  union { unsigned u; float f; } v; v.u = ((unsigned)h) << 16;
  return v.f;
}

__device__ __forceinline__ void gll16(const void* g, void* l) {
  __builtin_amdgcn_global_load_lds(
      (const __attribute__((address_space(1))) unsigned*)g,
      (__attribute__((address_space(3))) unsigned*)l, 16, 0, 0);
}

// ---------------- graph prep ----------------

__global__ void k_count2(const int* __restrict__ d1, const int* __restrict__ d2,
                         int* __restrict__ i1, int* __restrict__ i2) {
  int t = blockIdx.x * 256 + threadIdx.x;
  const int* d = blockIdx.y ? d2 : d1;
  int* ii = blockIdx.y ? i2 : i1;
  if (t < NE) atomicAdd(&ii[d[t]], 1);
}

// shfl-based block scan
__global__ void k_scan2(const int* __restrict__ ideg1, int* __restrict__ off1,
                        int* __restrict__ cur1, float* __restrict__ dinv1,
                        const int* __restrict__ ideg2, int* __restrict__ off2,
                        int* __restrict__ cur2, float* __restrict__ dinv2) {
  const int* indeg = blockIdx.x ? ideg2 : ideg1;
  int* off = blockIdx.x ? off2 : off1;
  int* cur = blockIdx.x ? cur2 : cur1;
  float* dinv = blockIdx.x ? dinv2 : dinv1;
  __shared__ int wsum[16];
  int t = threadIdx.x, lane = t & 63, wv = t >> 6;
  int carry = 0;
  for (int base = 0; base < NN; base += 1024) {
    int v = indeg[base + t];
    int sc = v;
#pragma unroll
    for (int d = 1; d < 64; d <<= 1) {
      int o = __shfl_up(sc, d);
      if (lane >= d) sc += o;
    }
    if (lane == 63) wsum[wv] = sc;
    __syncthreads();
    if (t < 16) {
      int w = wsum[t];
#pragma unroll
      for (int d = 1; d < 16; d <<= 1) {
        int o = __shfl_up(w, d);
        if (t >= d) w += o;
      }
      wsum[t] = w;
    }
    __syncthreads();
    int excl = carry + (wv ? wsum[wv - 1] : 0) + sc - v;
    off[base + t] = excl;
    cur[base + t] = excl;
    dinv[base + t] = 1.0f / sqrtf((float)(v + 1));  // +1 self loop
    carry += wsum[15];
    __syncthreads();
  }
  if (t == 0) off[NN] = carry;
}

__global__ void k_fill2(const int* __restrict__ s1, const int* __restrict__ d1,
                        int* __restrict__ c1, int* __restrict__ l1,
                        const int* __restrict__ s2, const int* __restrict__ d2,
                        int* __restrict__ c2, int* __restrict__ l2) {
  int t = blockIdx.x * 256 + threadIdx.x;
  const int* src = blockIdx.y ? s2 : s1;
  const int* dst = blockIdx.y ? d2 : d1;
  int* cur = blockIdx.y ? c2 : c1;
  int* out = blockIdx.y ? l2 : l1;
  if (t < NE) {
    int d = dst[t];
    int slot = atomicAdd(&cur[d], 1);
    out[slot] = src[t];
  }
}

// ---------------- weight transpose + split (all 10 matrices, one launch) ----------------

__global__ void k_split_w(const float* W11, const float* W21, const float* W12,
                          const float* W22, const float* q1, const float* k1,
                          const float* v1, const float* q2, const float* k2,
                          const float* v2, short* __restrict__ whi,
                          short* __restrict__ wlo) {
  int y = blockIdx.y;
  const float* src; int R, C, base;
  if (y == 0)      { src = W11; R = 128; C = 256; base = 0; }
  else if (y == 1) { src = W21; R = 128; C = 256; base = 32768; }
  else if (y == 2) { src = W12; R = 256; C = 64;  base = 65536; }
  else if (y == 3) { src = W22; R = 256; C = 64;  base = 81920; }
  else if (y == 4) { src = q1;  R = 64;  C = 64;  base = 98304; }
  else if (y == 5) { src = k1;  R = 64;  C = 64;  base = 102400; }
  else if (y == 6) { src = v1;  R = 64;  C = 64;  base = 106496; }
  else if (y == 7) { src = q2;  R = 64;  C = 64;  base = 110592; }
  else if (y == 8) { src = k2;  R = 64;  C = 64;  base = 114688; }
  else             { src = v2;  R = 64;  C = 64;  base = 118784; }
  int idx = blockIdx.x * 256 + threadIdx.x;
  if (idx >= R * C) return;
  int r = idx / C, c = idx % C;
  float x = src[idx];
  unsigned short h = f2bf(x);
  whi[base + c * R + r] = (short)h;
  wlo[base + c * R + r] = (short)f2bf(x - bf2f(h));
}

// ---------------- layer-1 aggregation on raw x (D=128), wave per node, both branches ----------------

__global__ __launch_bounds__(256) void k_agg1d(
    const float* __restrict__ x1, const float* __restrict__ x2,
    const int* __restrict__ off1, const int* __restrict__ srcl1,
    const float* __restrict__ dinv1, const int* __restrict__ off2,
    const int* __restrict__ srcl2, const float* __restrict__ dinv2,
    short* __restrict__ a1hi, short* __restrict__ a1lo,
    short* __restrict__ a2hi, short* __restrict__ a2lo) {
  int br = blockIdx.y;
  const float* x = br ? x2 : x1;
  const int* off = br ? off2 : off1;
  const int* srcl = br ? srcl2 : srcl1;
  const float* dinv = br ? dinv2 : dinv1;
  short* ahi = br ? a2hi : a1hi;
  short* alo = br ? a2lo : a1lo;
  int wave = threadIdx.x >> 6, lane = threadIdx.x & 63;
  int node = blockIdx.x * 4 + wave;
  float dn = dinv[node];
  const float2* xr = (const float2*)x;
  float ax, ay;
  { float2 v = xr[(size_t)node * 64 + lane]; ax = dn * v.x; ay = dn * v.y; }
  int p = off[node], e = off[node + 1];
  for (; p + 3 < e; p += 4) {
    int s0 = srcl[p], s1 = srcl[p + 1], s2 = srcl[p + 2], s3 = srcl[p + 3];
    float w0 = dinv[s0], w1 = dinv[s1], w2 = dinv[s2], w3 = dinv[s3];
    float2 v0 = xr[(size_t)s0 * 64 + lane], v1 = xr[(size_t)s1 * 64 + lane];
    float2 v2 = xr[(size_t)s2 * 64 + lane], v3 = xr[(size_t)s3 * 64 + lane];
    ax += w0 * v0.x + w1 * v1.x + w2 * v2.x + w3 * v3.x;
    ay += w0 * v0.y + w1 * v1.y + w2 * v2.y + w3 * v3.y;
  }
  for (; p < e; ++p) {
    int s = srcl[p];
    float w = dinv[s];
    float2 v = xr[(size_t)s * 64 + lane];
    ax += w * v.x; ay += w * v.y;
  }
  float ox = dn * ax, oy = dn * ay;
  unsigned short hx = f2bf(ox), hy = f2bf(oy);
  int o = node * 128 + lane * 2;
  *(short2*)(ahi + o) = make_short2((short)hx, (short)hy);
  *(short2*)(alo + o) = make_short2((short)f2bf(ox - bf2f(hx)),
                                    (short)f2bf(oy - bf2f(hy)));
}

// ---------------- layer-2 aggregation (D=64) + bias, wave per node, both branches ----------------

__global__ __launch_bounds__(256) void k_agg2d(
    const float* __restrict__ t1, const float* __restrict__ t2,
    const int* __restrict__ off1, const int* __restrict__ srcl1,
    const float* __restrict__ dinv1, const int* __restrict__ off2,
    const int* __restrict__ srcl2, const float* __restrict__ dinv2,
    const float* __restrict__ b12, const float* __restrict__ b22,
    short* __restrict__ g1hi, short* __restrict__ g1lo,
    short* __restrict__ g2hi, short* __restrict__ g2lo) {
  int br = blockIdx.y;
  const float* t = br ? t2 : t1;
  const int* off = br ? off2 : off1;
  const int* srcl = br ? srcl2 : srcl1;
  const float* dinv = br ? dinv2 : dinv1;
  const float* bias = br ? b22 : b12;
  short* ghi = br ? g2hi : g1hi;
  short* glo = br ? g2lo : g1lo;
  int wave = threadIdx.x >> 6, lane = threadIdx.x & 63;
  int node = blockIdx.x * 4 + wave;
  float dn = dinv[node];
  float acc = dn * t[(size_t)node * 64 + lane];
  int p = off[node], e = off[node + 1];
  for (; p + 3 < e; p += 4) {
    int s0 = srcl[p], s1 = srcl[p + 1], s2 = srcl[p + 2], s3 = srcl[p + 3];
    float w0 = dinv[s0], w1 = dinv[s1], w2 = dinv[s2], w3 = dinv[s3];
    acc += w0 * t[(size_t)s0 * 64 + lane] + w1 * t[(size_t)s1 * 64 + lane] +
           w2 * t[(size_t)s2 * 64 + lane] + w3 * t[(size_t)s3 * 64 + lane];
  }
  for (; p < e; ++p) {
    int s = srcl[p];
    acc += dinv[s] * t[(size_t)s * 64 + lane];
  }
  float o = dn * acc + bias[lane];
  unsigned short h = f2bf(o);
  ghi[(size_t)node * 64 + lane] = (short)h;
  glo[(size_t)node * 64 + lane] = (short)f2bf(o - bf2f(h));
}

// ---------------- GCN layer-1 GEMM (K=128, N=256, bias+relu, hl out), both branches ----------------

__global__ __launch_bounds__(64) void k_gemmL1(
    const short* __restrict__ a1hi, const short* __restrict__ a1lo,
    const short* __restrict__ a2hi, const short* __restrict__ a2lo,
    const short* __restrict__ whi, const short* __restrict__ wlo,
    const float* __restrict__ b11, const float* __restrict__ b21,
    short* __restrict__ h1hi, short* __restrict__ h1lo,
    short* __restrict__ h2hi, short* __restrict__ h2lo) {
  int br = blockIdx.z;
  const short* Ahi = br ? a2hi : a1hi;
  const short* Alo = br ? a2lo : a1lo;
  const short* Bh = whi + (br ? 32768 : 0);
  const short* Bl = wlo + (br ? 32768 : 0);
  const float* bias = br ? b21 : b11;
  short* Chi = br ? h2hi : h1hi;
  short* Clo = br ? h2lo : h1lo;
  int lane = threadIdx.x;
  int lo16 = lane & 15, hi4 = lane >> 4;
  int r0 = blockIdx.x * 16;
  int c0 = blockIdx.y * 64;
  bfrag ah[4], al[4];
  const char* abh = (const char*)Ahi + ((size_t)(r0 + lo16) * 128 + hi4 * 8) * 2;
  const char* abl = (const char*)Alo + ((size_t)(r0 + lo16) * 128 + hi4 * 8) * 2;
#pragma unroll
  for (int ks = 0; ks < 4; ++ks) {
    ah[ks] = *(const bfrag*)(abh + ks * 64);
    al[ks] = *(const bfrag*)(abl + ks * 64);
  }
  f32x4 z = {0.f, 0.f, 0.f, 0.f};
  f32x4 acc[4] = {z, z, z, z};
#pragma unroll
  for (int c = 0; c < 4; ++c) {
    const char* bbh = (const char*)Bh + ((size_t)(c0 + c * 16 + lo16) * 128 + hi4 * 8) * 2;
    const char* bbl = (const char*)Bl + ((size_t)(c0 + c * 16 + lo16) * 128 + hi4 * 8) * 2;
#pragma unroll
    for (int ks = 0; ks < 4; ++ks) {
      bfrag bh = *(const bfrag*)(bbh + ks * 64);
      bfrag bl = *(const bfrag*)(bbl + ks * 64);
      acc[c] = MFMA(ah[ks], bh, acc[c]);
      acc[c] = MFMA(ah[ks], bl, acc[c]);
      acc[c] = MFMA(al[ks], bh, acc[c]);
    }
  }
#pragma unroll
  for (int c = 0; c < 4; ++c) {
    int col = c0 + c * 16 + lo16;
    float bv = bias[col];
#pragma unroll
    for (int r = 0; r < 4; ++r) {
      int row = r0 + hi4 * 4 + r;
      float v = fmaxf(acc[c][r] + bv, 0.f);
      unsigned short h = f2bf(v);
      Chi[(size_t)row * 256 + col] = (short)h;
      Clo[(size_t)row * 256 + col] = (short)f2bf(v - bf2f(h));
    }
  }
}

// ---------------- GCN layer-2 GEMM (K=256, N=64, f32 out), both branches ----------------

__global__ __launch_bounds__(64) void k_gemmL2(
    const short* __restrict__ h1hi, const short* __restrict__ h1lo,
    const short* __restrict__ h2hi, const short* __restrict__ h2lo,
    const short* __restrict__ whi, const short* __restrict__ wlo,
    float* __restrict__ t1, float* __restrict__ t2) {
  int br = blockIdx.y;
  const short* Ahi = br ? h2hi : h1hi;
  const short* Alo = br ? h2lo : h1lo;
  const short* Bh = whi + (br ? 81920 : 65536);
  const short* Bl = wlo + (br ? 81920 : 65536);
  float* Cf = br ? t2 : t1;
  int lane = threadIdx.x;
  int lo16 = lane & 15, hi4 = lane >> 4;
  int r0 = blockIdx.x * 16;
  bfrag ah[8], al[8];
  const char* abh = (const char*)Ahi + ((size_t)(r0 + lo16) * 256 + hi4 * 8) * 2;
  const char* abl = (const char*)Alo + ((size_t)(r0 + lo16) * 256 + hi4 * 8) * 2;
#pragma unroll
  for (int ks = 0; ks < 8; ++ks) {
    ah[ks] = *(const bfrag*)(abh + ks * 64);
    al[ks] = *(const bfrag*)(abl + ks * 64);
  }
  f32x4 z = {0.f, 0.f, 0.f, 0.f};
  f32x4 acc[4] = {z, z, z, z};
#pragma unroll
  for (int c = 0; c < 4; ++c) {
    const char* bbh = (const char*)Bh + ((size_t)(c * 16 + lo16) * 256 + hi4 * 8) * 2;
    const char* bbl = (const char*)Bl + ((size_t)(c * 16 + lo16) * 256 + hi4 * 8) * 2;
#pragma unroll
    for (int ks = 0; ks < 8; ++ks) {
      bfrag bh = *(const bfrag*)(bbh + ks * 64);
      bfrag bl = *(const bfrag*)(bbl + ks * 64);
      acc[c] = MFMA(ah[ks], bh, acc[c]);
      acc[c] = MFMA(ah[ks], bl, acc[c]);
      acc[c] = MFMA(al[ks], bh, acc[c]);
    }
  }
#pragma unroll
  for (int c = 0; c < 4; ++c) {
    int col = c * 16 + lo16;
#pragma unroll
    for (int r = 0; r < 4; ++r)
      Cf[(size_t)(r0 + hi4 * 4 + r) * 64 + col] = acc[c][r];
  }
}

// ---------------- QKV projections; V writes transposed hi/lo directly ----------------

__global__ __launch_bounds__(64) void k_qkv(
    const short* __restrict__ Aqhi, const short* __restrict__ Aqlo,
    const short* __restrict__ Akhi, const short* __restrict__ Aklo,
    const short* __restrict__ Avhi, const short* __restrict__ Avlo,
    const short* __restrict__ whi, const short* __restrict__ wlo,
    int bq, int bk, int bv,
    short* __restrict__ Qhi, short* __restrict__ Qlo,
    short* __restrict__ Khi, short* __restrict__ Klo,
    short* __restrict__ Vthi, short* __restrict__ Vtlo) {
  int y = blockIdx.y;
  const short *Ah, *Al;
  int boff;
  if (y == 0)      { Ah = Aqhi; Al = Aqlo; boff = bq; }
  else if (y == 1) { Ah = Akhi; Al = Aklo; boff = bk; }
  else             { Ah = Avhi; Al = Avlo; boff = bv; }
  const short* Bh = whi + boff;
  const short* Bl = wlo + boff;
  int lane = threadIdx.x;
  int lo16 = lane & 15, hi4 = lane >> 4;
  int r0 = blockIdx.x * 16;
  bfrag ah0, ah1, al0, al1;
  {
    const char* a = (const char*)(Ah + (size_t)(r0 + lo16) * 64 + hi4 * 8);
    const char* b = (const char*)(Al + (size_t)(r0 + lo16) * 64 + hi4 * 8);
    ah0 = *(const bfrag*)a; ah1 = *(const bfrag*)(a + 64);
    al0 = *(const bfrag*)b; al1 = *(const bfrag*)(b + 64);
  }
  f32x4 z = {0.f, 0.f, 0.f, 0.f};
  f32x4 acc[4] = {z, z, z, z};
#pragma unroll
  for (int c = 0; c < 4; ++c) {
    const char* bbh = (const char*)(Bh + (size_t)(c * 16 + lo16) * 64 + hi4 * 8);
    const char* bbl = (const char*)(Bl + (size_t)(c * 16 + lo16) * 64 + hi4 * 8);
    bfrag bh0 = *(const bfrag*)bbh, bh1 = *(const bfrag*)(bbh + 64);
    bfrag bl0 = *(const bfrag*)bbl, bl1 = *(const bfrag*)(bbl + 64);
    acc[c] = MFMA(ah0, bh0, acc[c]);
    acc[c] = MFMA(ah1, bh1, acc[c]);
    acc[c] = MFMA(ah0, bl0, acc[c]);
    acc[c] = MFMA(ah1, bl1, acc[c]);
    acc[c] = MFMA(al0, bh0, acc[c]);
    acc[c] = MFMA(al1, bh1, acc[c]);
  }
  if (y == 2) {
#pragma unroll
    for (int c = 0; c < 4; ++c) {
      int col = c * 16 + lo16;
      short4 vh, vl;
      float v0 = acc[c][0], v1 = acc[c][1], v2 = acc[c][2], v3 = acc[c][3];
      unsigned short h0 = f2bf(v0), h1 = f2bf(v1), h2 = f2bf(v2), h3 = f2bf(v3);
      vh = make_short4((short)h0, (short)h1, (short)h2, (short)h3);
      vl = make_short4((short)f2bf(v0 - bf2f(h0)), (short)f2bf(v1 - bf2f(h1)),
                       (short)f2bf(v2 - bf2f(h2)), (short)f2bf(v3 - bf2f(h3)));
      size_t o = (size_t)col * NN + r0 + hi4 * 4;
      *(short4*)(Vthi + o) = vh;
      *(short4*)(Vtlo + o) = vl;
    }
  } else {
    short* oh = (y == 0) ? Qhi : Khi;
    short* ol = (y == 0) ? Qlo : Klo;
#pragma unroll
    for (int c = 0; c < 4; ++c) {
      int col = c * 16 + lo16;
#pragma unroll
      for (int r = 0; r < 4; ++r) {
        int row = r0 + hi4 * 4 + r;
        float v = acc[c][r];
        unsigned short h = f2bf(v);
        oh[(size_t)row * 64 + col] = (short)h;
        ol[(size_t)row * 64 + col] = (short)f2bf(v - bf2f(h));
      }
    }
  }
}

// ---------------- MFMA flash attention v8 ----------------
// v7 + (a) lazy rowmax reduce (shfl tree only when a rescale triggers —
// bit-identical), (b) softmax denominator via ones-column MFMA (consistent
// rounded weights, no per-step VALU extraction, no end shfl reduce).

__global__ __launch_bounds__(256) void k_attn_v8(
    const short* __restrict__ Qhi, const short* __restrict__ Qlo,
    const short* __restrict__ Khi_g, const short* __restrict__ Klo_g,
    const short* __restrict__ Vthi_g, const short* __restrict__ Vtlo_g,
    float* __restrict__ Opart, float* __restrict__ mpart, float* __restrict__ lpart) {
  __shared__ short skh[2][32 * 64], skl[2][32 * 64];
  __shared__ short svh[2][64 * 32], svl[2][64 * 32];
  __shared__ short plds[8][16 * 40];
  const int tid = threadIdx.x;
  const int wave = tid >> 6, lane = tid & 63;
  const int lo16 = lane & 15, hi4 = lane >> 4;
  const int q0 = blockIdx.x * 128 + wave * 32;
  const int j0 = blockIdx.y * (NN / NCH);
  short* mypA = plds[wave * 2];
  short* mypB = plds[wave * 2 + 1];

  const int krow = wave * 8 + (lane >> 3);
  const int kcbs = ((lane & 7) * 16) ^ ((krow & 7) << 4);
  const int vrow = wave * 16 + (lane >> 2);
  const int vcbs = ((lane & 3) * 16) ^ (((vrow >> 1) & 3) << 4);
  const char* gka = (const char*)Khi_g + (size_t)(j0 + krow) * 128 + kcbs;
  const char* gkb = (const char*)Klo_g + (size_t)(j0 + krow) * 128 + kcbs;
  const char* gva = (const char*)Vthi_g + (size_t)vrow * (NN * 2) + (size_t)j0 * 2 + vcbs;
  const char* gvb = (const char*)Vtlo_g + (size_t)vrow * (NN * 2) + (size_t)j0 * 2 + vcbs;

#define STAGE(buf, s)                                                \
  do {                                                               \
    gll16(gka + (size_t)(s) * 4096, (char*)skh[buf] + wave * 1024);  \
    gll16(gkb + (size_t)(s) * 4096, (char*)skl[buf] + wave * 1024);  \
    gll16(gva + (s) * 64, (char*)svh[buf] + wave * 1024);            \
    gll16(gvb + (s) * 64, (char*)svl[buf] + wave * 1024);            \
  } while (0)

  const bfrag* qphA = (const bfrag*)(Qhi + (size_t)(q0 + lo16) * 64 + hi4 * 8);
  const bfrag* qplA = (const bfrag*)(Qlo + (size_t)(q0 + lo16) * 64 + hi4 * 8);
  const bfrag* qphB = (const bfrag*)(Qhi + (size_t)(q0 + 16 + lo16) * 64 + hi4 * 8);
  const bfrag* qplB = (const bfrag*)(Qlo + (size_t)(q0 + 16 + lo16) * 64 + hi4 * 8);
  bfrag qh0A = qphA[0], qh1A = qphA[4], ql0A = qplA[0], ql1A = qplA[4];
  bfrag qh0B = qphB[0], qh1B = qphB[4], ql0B = qplB[0], ql1B = qplB[4];

  bfrag onesf;
#pragma unroll
  for (int i = 0; i < 8; ++i) onesf[i] = (short)0x3F80;  // bf16 1.0

  f32x4 z = {0.f, 0.f, 0.f, 0.f};
  f32x4 oaccA[4] = {z, z, z, z}, oaccB[4] = {z, z, z, z};
  f32x4 oextA = z, oextB = z;  // ones-column row-sum accumulators
  float mrunA[4] = {-1e30f, -1e30f, -1e30f, -1e30f};
  float mrunB[4] = {-1e30f, -1e30f, -1e30f, -1e30f};

#define SMAX(sa, mrun, oacc, oext, myp, pa)                                   \
  do {                                                                        \
    _Pragma("unroll") for (int t = 0; t < 2; ++t)                             \
      _Pragma("unroll") for (int r = 0; r < 4; ++r) {                         \
        float v = sa[t][r];                                                   \
        sa[t][r] = fmaxf(v, 0.01f * v);                                       \
      }                                                                       \
    float pm[4];                                                              \
    _Pragma("unroll") for (int r = 0; r < 4; ++r)                             \
        pm[r] = fmaxf(sa[0][r], sa[1][r]);                                    \
    bool rb = false;                                                          \
    _Pragma("unroll") for (int r = 0; r < 4; ++r) rb |= (pm[r] > mrun[r] + 4.f); \
    if (__any(rb)) { /* rare: full reduce + rescale (bit-identical to v7) */  \
      _Pragma("unroll") for (int mask = 1; mask <= 8; mask <<= 1)             \
        _Pragma("unroll") for (int r = 0; r < 4; ++r)                         \
          pm[r] = fmaxf(pm[r], __shfl_xor(pm[r], mask));                      \
      _Pragma("unroll") for (int r = 0; r < 4; ++r) {                         \
        float nm = (pm[r] > mrun[r] + 4.f) ? pm[r] : mrun[r];                 \
        float c_ = __expf(mrun[r] - nm);                                      \
        _Pragma("unroll") for (int c = 0; c < 4; ++c) oacc[c][r] *= c_;       \
        oext[r] *= c_;                                                        \
        mrun[r] = nm;                                                         \
      }                                                                       \
    }                                                                         \
    float p0[4], p1[4];                                                       \
    _Pragma("unroll") for (int r = 0; r < 4; ++r) {                           \
      p0[r] = __expf(sa[0][r] - mrun[r]);                                     \
      p1[r] = __expf(sa[1][r] - mrun[r]);                                     \
    }                                                                         \
    unsigned pq0, pq1, pq2, pq3;                                              \
    CVTPK(pq0, p0[0], p0[1]);                                                 \
    CVTPK(pq1, p0[2], p0[3]);                                                 \
    CVTPK(pq2, p1[0], p1[1]);                                                 \
    CVTPK(pq3, p1[2], p1[3]);                                                 \
    {                                                                         \
      int rb_ = hi4 * 4;                                                      \
      myp[(rb_ + 0) * 40 + lo16] = (short)pq0;                                \
      myp[(rb_ + 1) * 40 + lo16] = (short)(pq0 >> 16);                        \
      myp[(rb_ + 2) * 40 + lo16] = (short)pq1;                                \
      myp[(rb_ + 3) * 40 + lo16] = (short)(pq1 >> 16);                        \
      myp[(rb_ + 0) * 40 + 16 + lo16] = (short)pq2;                           \
      myp[(rb_ + 1) * 40 + 16 + lo16] = (short)(pq2 >> 16);                   \
      myp[(rb_ + 2) * 40 + 16 + lo16] = (short)pq3;                           \
      myp[(rb_ + 3) * 40 + 16 + lo16] = (short)(pq3 >> 16);                   \
    }                                                                         \
    pa = *(const bfrag*)(myp + lo16 * 40 + hi4 * 8);                          \
  } while (0)

  auto step = [&](int buf) {
    const char* kh = (const char*)skh[buf];
    const char* kl = (const char*)skl[buf];
    f32x4 saA[2], saB[2];
    __builtin_amdgcn_s_setprio(1);
#pragma unroll
    for (int t = 0; t < 2; ++t) {
      int jr = 16 * t + lo16;
      int sw = (jr & 7) << 4;
      const char* rowh = kh + jr * 128;
      const char* rowl = kl + jr * 128;
      bfrag kf0 = *(const bfrag*)(rowh + ((hi4 * 16) ^ sw));
      bfrag kf1 = *(const bfrag*)(rowh + ((64 + hi4 * 16) ^ sw));
      bfrag kg0 = *(const bfrag*)(rowl + ((hi4 * 16) ^ sw));
      bfrag kg1 = *(const bfrag*)(rowl + ((64 + hi4 * 16) ^ sw));
      f32x4 a = z;
      a = MFMA(qh0A, kf0, a);
      a = MFMA(qh1A, kf1, a);
      a = MFMA(qh0A, kg0, a);
      a = MFMA(qh1A, kg1, a);
      a = MFMA(ql0A, kf0, a);
      a = MFMA(ql1A, kf1, a);
      saA[t] = a;
      f32x4 b = z;
      b = MFMA(qh0B, kf0, b);
      b = MFMA(qh1B, kf1, b);
      b = MFMA(qh0B, kg0, b);
      b = MFMA(qh1B, kg1, b);
      b = MFMA(ql0B, kf0, b);
      b = MFMA(ql1B, kf1, b);
      saB[t] = b;
    }
    __builtin_amdgcn_s_setprio(0);
    bfrag paA, paB;
    SMAX(saA, mrunA, oaccA, oextA, mypA, paA);
    SMAX(saB, mrunB, oaccB, oextB, mypB, paB);
    const char* vh = (const char*)svh[buf];
    const char* vl = (const char*)svl[buf];
    __builtin_amdgcn_s_setprio(1);
#pragma unroll
    for (int c = 0; c < 4; ++c) {
      int dv = 16 * c + lo16;
      int svw = ((dv >> 1) & 3) << 4;
      bfrag vhf = *(const bfrag*)(vh + dv * 64 + ((hi4 * 16) ^ svw));
      bfrag vlf = *(const bfrag*)(vl + dv * 64 + ((hi4 * 16) ^ svw));
      oaccA[c] = MFMA(paA, vhf, oaccA[c]);
      oaccA[c] = MFMA(paA, vlf, oaccA[c]);
      oaccB[c] = MFMA(paB, vhf, oaccB[c]);
      oaccB[c] = MFMA(paB, vlf, oaccB[c]);
    }
    // denominator: row-sum of the SAME rounded P via ones-column MFMA
    oextA = MFMA(paA, onesf, oextA);
    oextB = MFMA(paB, onesf, oextB);
    __builtin_amdgcn_s_setprio(0);
  };

  STAGE(0, 0);
  STAGE(1, 1);
  for (int s = 0; s < NS - 1; ++s) {
    const int buf = s & 1;
    asm volatile("s_waitcnt vmcnt(4)" ::: "memory");
    __builtin_amdgcn_s_barrier();
    __builtin_amdgcn_sched_barrier(0);
    step(buf);
    __builtin_amdgcn_sched_barrier(0);
    __builtin_amdgcn_s_barrier();
    if (s + 2 < NS) STAGE(buf, s + 2);
  }
  asm volatile("s_waitcnt vmcnt(0)" ::: "memory");
  __builtin_amdgcn_s_barrier();
  __builtin_amdgcn_sched_barrier(0);
  step((NS - 1) & 1);
#undef STAGE
#undef SMAX

#pragma unroll
  for (int c = 0; c < 4; ++c)
#pragma unroll
    for (int r = 0; r < 4; ++r) {
      Opart[((size_t)blockIdx.y * NN + q0 + hi4 * 4 + r) * 64 + 16 * c + lo16] = oaccA[c][r];
      Opart[((size_t)blockIdx.y * NN + q0 + 16 + hi4 * 4 + r) * 64 + 16 * c + lo16] = oaccB[c][r];
    }
  if (lo16 == 0) {
#pragma unroll
    for (int r = 0; r < 4; ++r) {
      mpart[blockIdx.y * NN + q0 + hi4 * 4 + r] = mrunA[r];
      lpart[blockIdx.y * NN + q0 + hi4 * 4 + r] = oextA[r];
      mpart[blockIdx.y * NN + q0 + 16 + hi4 * 4 + r] = mrunB[r];
      lpart[blockIdx.y * NN + q0 + 16 + hi4 * 4 + r] = oextB[r];
    }
  }
}

// combine partials -> o hi/lo bf16
__global__ void k_comb(const float* __restrict__ Opart,
                       const float* __restrict__ mpart,
                       const float* __restrict__ lpart,
                       short* __restrict__ Ohi, short* __restrict__ Olo) {
  int row = blockIdx.x * 4 + (threadIdx.x >> 6);
  int d = threadIdx.x & 63;
  float M = -1e30f;
  for (int i = 0; i < NCH; ++i) M = fmaxf(M, mpart[i * NN + row]);
  float L = 0.f, acc = 0.f;
  for (int i = 0; i < NCH; ++i) {
    float w = __expf(mpart[i * NN + row] - M);
    L += w * lpart[i * NN + row];
    acc += w * Opart[((size_t)i * NN + row) * 64 + d];
  }
  float o = acc / L;
  unsigned short h = f2bf(o);
  Ohi[(size_t)row * 64 + d] = (short)h;
  Olo[(size_t)row * 64 + d] = (short)f2bf(o - bf2f(h));
}

// ---------------- logits = o1 @ o2^T; 2 i-tiles/wave, B ping-pong ----------------

__global__ __launch_bounds__(256) void k_outer(const short* __restrict__ o1hi,
                                               const short* __restrict__ o1lo,
                                               const short* __restrict__ o2hi,
                                               const short* __restrict__ o2lo,
                                               float* __restrict__ out) {
  int wave = threadIdx.x >> 6, lane = threadIdx.x & 63;
  int lo16 = lane & 15, hi4 = lane >> 4;
  int i0 = blockIdx.x * 128 + wave * 32;
  const bfrag* aphA = (const bfrag*)(o1hi + (size_t)(i0 + lo16) * 64 + hi4 * 8);
  const bfrag* aplA = (const bfrag*)(o1lo + (size_t)(i0 + lo16) * 64 + hi4 * 8);
  const bfrag* aphB = (const bfrag*)(o1hi + (size_t)(i0 + 16 + lo16) * 64 + hi4 * 8);
  const bfrag* aplB = (const bfrag*)(o1lo + (size_t)(i0 + 16 + lo16) * 64 + hi4 * 8);
  bfrag ah0A = aphA[0], ah1A = aphA[4], al0A = aplA[0], al1A = aplA[4];
  bfrag ah0B = aphB[0], ah1B = aphB[4], al0B = aplB[0], al1B = aplB[4];
  f32x4 z = {0.f, 0.f, 0.f, 0.f};
  int jbase = blockIdx.y * (NN / 16);

#define LOADB(JV, BH0, BH1, BL0, BL1)                                        \
  do {                                                                       \
    const bfrag* bph = (const bfrag*)(o2hi + (size_t)((JV) + lo16) * 64 + hi4 * 8); \
    const bfrag* bpl = (const bfrag*)(o2lo + (size_t)((JV) + lo16) * 64 + hi4 * 8); \
    BH0 = bph[0]; BH1 = bph[4]; BL0 = bpl[0]; BL1 = bpl[4];                  \
  } while (0)

#define COMP(JV, BH0, BH1, BL0, BL1)                                  \
  do {                                                                \
    f32x4 accA = z, accB = z;                                         \
    accA = MFMA(ah0A, BH0, accA);                                     \
    accA = MFMA(ah1A, BH1, accA);                                     \
    accA = MFMA(ah0A, BL0, accA);                                     \
    accA = MFMA(ah1A, BL1, accA);                                     \
    accA = MFMA(al0A, BH0, accA);                                     \
    accA = MFMA(al1A, BH1, accA);                                     \
    accB = MFMA(ah0B, BH0, accB);                                     \
    accB = MFMA(ah1B, BH1, accB);                                     \
    accB = MFMA(ah0B, BL0, accB);                                     \
    accB = MFMA(ah1B, BL1, accB);                                     \
    accB = MFMA(al0B, BH0, accB);                                     \
    accB = MFMA(al1B, BH1, accB);                                     \
    _Pragma("unroll")                                                 \
    for (int r = 0; r < 4; ++r) {                                     \
      out[(size_t)(i0 + hi4 * 4 + r) * NN + (JV) + lo16] = accA[r];   \
      out[(size_t)(i0 + 16 + hi4 * 4 + r) * NN + (JV) + lo16] = accB[r]; \
    }                                                                 \
  } while (0)

  bfrag pah0, pah1, pal0, pal1, pbh0, pbh1, pbl0, pbl1;
  LOADB(jbase, pah0, pah1, pal0, pal1);
  for (int jt = 0; jt < NN / 16 / 16; jt += 2) {
    int ja = jbase + jt * 16;
    LOADB(ja + 16, pbh0, pbh1, pbl0, pbl1);
    COMP(ja, pah0, pah1, pal0, pal1);
    if (jt + 2 < NN / 16 / 16) LOADB(ja + 32, pah0, pah1, pal0, pal1);
    COMP(ja + 16, pbh0, pbh1, pbl0, pbl1);
  }
#undef LOADB
#undef COMP
}

// ---------------- launch ----------------

extern "C" void kernel_launch(void* const* d_in, const int* in_sizes, int n_in,
                              void* d_out, int out_size, void* d_ws, size_t ws_size,
                              hipStream_t stream) {
  const int* g1 = (const int*)d_in[0];
  const int* g2 = (const int*)d_in[1];
  const float* x1 = (const float*)d_in[2];
  const float* x2 = (const float*)d_in[3];
  const float* W11 = (const float*)d_in[4];
  const float* b11 = (const float*)d_in[5];
  const float* W12 = (const float*)d_in[6];
  const float* b12 = (const float*)d_in[7];
  const float* W21 = (const float*)d_in[8];
  const float* b21 = (const float*)d_in[9];
  const float* W22 = (const float*)d_in[10];
  const float* b22 = (const float*)d_in[11];
  const float* q1 = (const float*)d_in[12];
  const float* k1 = (const float*)d_in[13];
  const float* v1 = (const float*)d_in[14];
  const float* q2 = (const float*)d_in[15];
  const float* k2 = (const float*)d_in[16];
  const float* v2 = (const float*)d_in[17];

  char* ob = (char*)d_out;
  const size_t MB = 1u << 20;
  int* srcl1 = (int*)(ob + 0 * MB);
  int* srcl2 = (int*)(ob + 1 * MB);
  char* small = ob + 2 * MB;
  int* ideg1 = (int*)(small);
  int* ideg2 = (int*)(small + (32u << 10));
  int* off1 = (int*)(small + (64u << 10));
  int* off2 = (int*)(small + (128u << 10));
  int* cur1 = (int*)(small + (192u << 10));
  int* cur2 = (int*)(small + (256u << 10));
  float* dinv1 = (float*)(small + (320u << 10));
  float* dinv2 = (float*)(small + (384u << 10));
  short* whi = (short*)(ob + 3 * MB);
  short* wlo = (short*)(ob + 3 * MB + (512u << 10));
  short* a1hi = (short*)(ob + 4 * MB);
  short* a1lo = (short*)(ob + 6 * MB);
  short* a2hi = (short*)(ob + 8 * MB);
  short* a2lo = (short*)(ob + 10 * MB);
  short* h1hi = (short*)(ob + 12 * MB);
  short* h1lo = (short*)(ob + 16 * MB);
  short* h2hi = (short*)(ob + 20 * MB);
  short* h2lo = (short*)(ob + 24 * MB);
  float* tbuf1 = (float*)(ob + 28 * MB);
  float* tbuf2 = (float*)(ob + 30 * MB);
  short* g1hi = (short*)(ob + 32 * MB);
  short* g1lo = (short*)(ob + 33 * MB);
  short* g2hi = (short*)(ob + 34 * MB);
  short* g2lo = (short*)(ob + 35 * MB);
  short* Qhi = (short*)(ob + 36 * MB);
  short* Qlo = (short*)(ob + 37 * MB);
  short* Khi = (short*)(ob + 38 * MB);
  short* Klo = (short*)(ob + 39 * MB);
  short* Vthi = (short*)(ob + 40 * MB);
  short* Vtlo = (short*)(ob + 41 * MB);
  float* Opart = (float*)(ob + 42 * MB);         // 16MB (8 x 8192 x 64)
  float* mpart = (float*)(ob + 58 * MB);         // 256KB
  float* lpart = (float*)(ob + 58 * MB + (256u << 10));
  short* o1hi = (short*)d_ws;
  short* o1lo = (short*)((char*)d_ws + 1 * MB);
  short* o2hi = (short*)((char*)d_ws + 2 * MB);
  short* o2lo = (short*)((char*)d_ws + 3 * MB);

  hipMemsetAsync(ideg1, 0, 64u << 10, stream);
  k_count2<<<dim3(1024, 2), 256, 0, stream>>>(g1 + NE, g2 + NE, ideg1, ideg2);
  k_scan2<<<2, 1024, 0, stream>>>(ideg1, off1, cur1, dinv1, ideg2, off2, cur2, dinv2);
  k_fill2<<<dim3(1024, 2), 256, 0, stream>>>(g1, g1 + NE, cur1, srcl1,
                                             g2, g2 + NE, cur2, srcl2);
  k_split_w<<<dim3(128, 10), 256, 0, stream>>>(W11, W21, W12, W22, q1, k1, v1,
                                               q2, k2, v2, whi, wlo);

  k_agg1d<<<dim3(2048, 2), 256, 0, stream>>>(x1, x2, off1, srcl1, dinv1,
                                             off2, srcl2, dinv2,
                                             a1hi, a1lo, a2hi, a2lo);
  k_gemmL1<<<dim3(512, 4, 2), 64, 0, stream>>>(a1hi, a1lo, a2hi, a2lo, whi, wlo,
                                               b11, b21, h1hi, h1lo, h2hi, h2lo);
  k_gemmL2<<<dim3(512, 2), 64, 0, stream>>>(h1hi, h1lo, h2hi, h2lo, whi, wlo,
                                            tbuf1, tbuf2);
  k_agg2d<<<dim3(2048, 2), 256, 0, stream>>>(tbuf1, tbuf2, off1, srcl1, dinv1,
                                             off2, srcl2, dinv2, b12, b22,
                                             g1hi, g1lo, g2hi, g2lo);

  // cross attention 1: Q=g1@q1, K=g2@k1, V=g1@v1 -> o1
  k_qkv<<<dim3(512, 3), 64, 0, stream>>>(g1hi, g1lo, g2hi, g2lo, g1hi, g1lo,
                                         whi, wlo, 98304, 102400, 106496,
                                         Qhi, Qlo, Khi, Klo, Vthi, Vtlo);
  k_attn_v8<<<dim3(64, NCH), 256, 0, stream>>>(Qhi, Qlo, Khi, Klo, Vthi, Vtlo,
                                               Opart, mpart, lpart);
  k_comb<<<2048, 256, 0, stream>>>(Opart, mpart, lpart, o1hi, o1lo);

  // cross attention 2: Q=g2@q2, K=o1@k2, V=g2@v2 -> o2
  k_qkv<<<dim3(512, 3), 64, 0, stream>>>(g2hi, g2lo, o1hi, o1lo, g2hi, g2lo,
                                         whi, wlo, 110592, 114688, 118784,
                                         Qhi, Qlo, Khi, Klo, Vthi, Vtlo);
  k_attn_v8<<<dim3(64, NCH), 256, 0, stream>>>(Qhi, Qlo, Khi, Klo, Vthi, Vtlo,
                                               Opart, mpart, lpart);
  k_comb<<<2048, 256, 0, stream>>>(Opart, mpart, lpart, o2hi, o2lo);

  // logits = o1 @ o2^T -> d_out (overwrites all scratch)
  k_outer<<<dim3(64, 16), 256, 0, stream>>>(o1hi, o1lo, o2hi, o2lo, (float*)d_out);

  (void)in_sizes; (void)n_in; (void)out_size; (void)ws_size;
}